// Round 8
// baseline (255.574 us; speedup 1.0000x reference)
//
#include <hip/hip_runtime.h>
#include <stdint.h>

#define SEQLEN 4096
#define DMODEL 1024
#define NHEADS 16
#define DKDIM  64

typedef unsigned short u16;
typedef unsigned int   u32;
using f32x4 = __attribute__((ext_vector_type(4))) float;
using i32x4 = __attribute__((ext_vector_type(4))) int;
using i32x2 = __attribute__((ext_vector_type(2))) int;
using u16x8 = __attribute__((ext_vector_type(8))) unsigned short;

__device__ __forceinline__ float bf2f(u16 u) {
    u32 x = ((u32)u) << 16;
    return __builtin_bit_cast(float, x);
}
__device__ __forceinline__ u16 f2bf(float f) {
    u32 x = __builtin_bit_cast(u32, f);
    u32 r = x + 0x7fffu + ((x >> 16) & 1u);   // RNE
    return (u16)(r >> 16);
}
__device__ __forceinline__ float exp2a(float x) {
    float r; asm("v_exp_f32 %0, %1" : "=v"(r) : "v"(x)); return r;
}
__device__ __forceinline__ u32 cvtpk(float lo, float hi) {
    u32 r; asm("v_cvt_pk_bf16_f32 %0, %1, %2" : "=v"(r) : "v"(lo), "v"(hi)); return r;
}

// 16x16x32: A lane holds A[lane&15][(lane>>4)*8+j]; B: B[(lane>>4)*8+j][lane&15];
// C/D: D[(lane>>4)*4+r][lane&15]
__device__ __forceinline__ void mfma_bf16(f32x4& d, i32x4 a, i32x4 b) {
    asm("v_mfma_f32_16x16x32_bf16 %0, %1, %2, %0" : "+v"(d) : "v"(a), "v"(b));
}
// 16x16x16: A lane holds A[lane&15][(lane>>4)*4+j]; B: B[(lane>>4)*4+j][lane&15]
__device__ __forceinline__ void mfma16_bf16(f32x4& d, i32x2 a, i32x2 b) {
    asm("v_mfma_f32_16x16x16_bf16 %0, %1, %2, %0" : "+v"(d) : "v"(a), "v"(b));
}

// async global->LDS, 16B per lane; LDS dest = wave-uniform base + lane*16
#define ASYNC_COPY16(gsrc, ldst) \
    __builtin_amdgcn_global_load_lds((const __attribute__((address_space(1))) void*)(gsrc), \
                                     (__attribute__((address_space(3))) void*)(ldst), 16, 0, 0)

// ---------------- LayerNorm: h fp32 [4096][1024] -> hn bf16 ----------------
__global__ __launch_bounds__(256) void ln_kernel(const float* __restrict__ h,
                                                 const float* __restrict__ gamma,
                                                 const float* __restrict__ beta,
                                                 u16* __restrict__ hn) {
    int row = blockIdx.x;
    int t = threadIdx.x;
    float4 v = reinterpret_cast<const float4*>(h + (size_t)row * DMODEL)[t];
    float s  = v.x + v.y + v.z + v.w;
    float s2 = v.x*v.x + v.y*v.y + v.z*v.z + v.w*v.w;
#pragma unroll
    for (int off = 1; off < 64; off <<= 1) {
        s  += __shfl_xor(s, off);
        s2 += __shfl_xor(s2, off);
    }
    __shared__ float red[8];
    int wid = t >> 6, lane = t & 63;
    if (lane == 0) { red[wid] = s; red[4 + wid] = s2; }
    __syncthreads();
    s  = red[0] + red[1] + red[2] + red[3];
    s2 = red[4] + red[5] + red[6] + red[7];
    float mu   = s * (1.0f / DMODEL);
    float rstd = rsqrtf(s2 * (1.0f / DMODEL) - mu * mu + 1e-5f);
    float4 g = reinterpret_cast<const float4*>(gamma)[t];
    float4 b = reinterpret_cast<const float4*>(beta)[t];
    ushort4 o;
    o.x = f2bf((v.x - mu) * rstd * g.x + b.x);
    o.y = f2bf((v.y - mu) * rstd * g.y + b.y);
    o.z = f2bf((v.z - mu) * rstd * g.z + b.z);
    o.w = f2bf((v.w - mu) * rstd * g.w + b.w);
    reinterpret_cast<ushort4*>(hn + (size_t)row * DMODEL)[t] = o;
}

// ---- Weight transpose+convert (all 4 weights): W fp32 [K][N] -> Wt bf16 [N][K] ----
__global__ __launch_bounds__(256) void wconv_kernel(const float* __restrict__ Wq,
                                                    const float* __restrict__ Wk,
                                                    const float* __restrict__ Wv,
                                                    const float* __restrict__ Wo,
                                                    u16* __restrict__ wqkvT,
                                                    u16* __restrict__ woT) {
    int z = blockIdx.z;
    const float* W = (z == 0) ? Wq : (z == 1) ? Wk : (z == 2) ? Wv : Wo;
    u16* Wt = (z < 3) ? wqkvT + (size_t)z * DMODEL * DMODEL : woT;
    __shared__ float tile[32][33];
    int bx = blockIdx.x * 32;   // n
    int by = blockIdx.y * 32;   // k
    int tx = threadIdx.x & 31, ty = threadIdx.x >> 5;
#pragma unroll
    for (int i = 0; i < 32; i += 8)
        tile[ty + i][tx] = W[(size_t)(by + ty + i) * DMODEL + bx + tx];
    __syncthreads();
#pragma unroll
    for (int i = 0; i < 32; i += 8)
        Wt[(size_t)(bx + ty + i) * DMODEL + by + tx] = f2bf(tile[tx][ty + i]);
}

// ---------------- RoPE cos/sin tables: [4096][32] fp32 each ----------------
__global__ void rope_table_kernel(float* __restrict__ cosT, float* __restrict__ sinT) {
    int idx = blockIdx.x * 256 + threadIdx.x;
    int s = idx >> 5, i = idx & 31;
    float theta = powf(10000.0f, -2.0f * (float)i / 64.0f);
    float ang = (float)s * theta;
    cosT[idx] = cosf(ang);
    sinT[idx] = sinf(ang);
}

// ---------------- GEMM: 128x128 tile, BK=64, global_load_lds double-buffer ----------------
// EPI=0: merged QKV (Bt rows 0..3071). seg=bn>>3: 0=Q (RoPE, *log2e/8 -> o0),
//        1=K (RoPE -> o1), 2=V (write V^T [head][64][seq] -> o2).
// EPI=1: +bias +residual, fp32 [seq][1024] -> ofp.
template <int EPI>
__global__ __launch_bounds__(256) void gemm_kernel(const u16* __restrict__ A,
                                                   const u16* __restrict__ Bt,
                                                   const float* __restrict__ b0,
                                                   const float* __restrict__ b1,
                                                   const float* __restrict__ b2,
                                                   const float* __restrict__ resid,
                                                   const float* __restrict__ cosT,
                                                   const float* __restrict__ sinT,
                                                   u16* __restrict__ o0,
                                                   u16* __restrict__ o1,
                                                   u16* __restrict__ o2,
                                                   float* __restrict__ ofp) {
    __shared__ alignas(16) u16 As[2][128 * 64];
    __shared__ alignas(16) u16 Bs[2][128 * 64];
    int bm = blockIdx.x, bn = blockIdx.y;
    int tid = threadIdx.x;
    int wid = tid >> 6, lane = tid & 63;
    int wm = wid >> 1, wn = wid & 1;
    int t15 = lane & 15, g = lane >> 4;
    const u16* Abase = A  + (size_t)bm * 128 * DMODEL;
    const u16* Bbase = Bt + (size_t)bn * 128 * DMODEL;
    int srow = tid >> 3;          // 0..31 within each 32-row issue chunk
    int sslot = tid & 7;
    f32x4 acc[4][4] = {};

    // LDS[row][slot] = global[row][slot ^ (row&7)]  (slots of 8 elems = 16B)
#define GSTAGE(b, ks)                                                                    \
    {                                                                                    \
        _Pragma("unroll")                                                                \
        for (int i = 0; i < 4; i++) {                                                    \
            int row = i * 32 + srow;                                                     \
            int col = ((sslot ^ (row & 7)) * 8) + (ks);                                  \
            ASYNC_COPY16(Abase + (size_t)row * DMODEL + col, &As[b][i * 2048 + wid * 512]); \
            ASYNC_COPY16(Bbase + (size_t)row * DMODEL + col, &Bs[b][i * 2048 + wid * 512]); \
        }                                                                                \
    }

    GSTAGE(0, 0)
    __syncthreads();
    int buf = 0;
    for (int ks = 0; ks < DMODEL; ks += 64) {
        if (ks < DMODEL - 64) GSTAGE(buf ^ 1, ks + 64)
#pragma unroll
        for (int kk = 0; kk < 2; kk++) {
            i32x4 af[4], bfr[4];
#pragma unroll
            for (int mi = 0; mi < 4; mi++) {
                int row = wm * 64 + mi * 16 + t15;
                int sl = (kk * 4 + g) ^ (row & 7);
                af[mi] = *reinterpret_cast<const i32x4*>(&As[buf][row * 64 + sl * 8]);
            }
#pragma unroll
            for (int ni = 0; ni < 4; ni++) {
                int row = wn * 64 + ni * 16 + t15;
                int sl = (kk * 4 + g) ^ (row & 7);
                bfr[ni] = *reinterpret_cast<const i32x4*>(&Bs[buf][row * 64 + sl * 8]);
            }
            __builtin_amdgcn_s_setprio(1);
#pragma unroll
            for (int mi = 0; mi < 4; mi++)
#pragma unroll
                for (int ni = 0; ni < 4; ni++)
                    mfma_bf16(acc[mi][ni], af[mi], bfr[ni]);
            __builtin_amdgcn_s_setprio(0);
        }
        __syncthreads();
        buf ^= 1;
    }
#undef GSTAGE

    if (EPI == 0) {
        int seg = bn >> 3;                 // 0=Q 1=K 2=V
        int bnl = bn & 7;
        const float* bias = (seg == 0) ? b0 : (seg == 1) ? b1 : b2;
        if (seg < 2) {
            u16* o = (seg == 0) ? o0 : o1;
            float qs = (seg == 0) ? 0.18033688f : 1.0f;   // log2(e)/8 for Q
#pragma unroll
            for (int mi = 0; mi < 4; mi++) {
#pragma unroll
                for (int nl = 0; nl < 2; nl++) {
                    int n10 = bnl * 128 + wn * 64 + nl * 16 + t15;  // d&63 in 0..31
                    int head = n10 >> 6;
                    int dA = n10 & 63, dB = dA + 32;
                    float bvA = bias[n10], bvB = bias[n10 + 32];
#pragma unroll
                    for (int r = 0; r < 4; r++) {
                        int m = bm * 128 + wm * 64 + mi * 16 + g * 4 + r;
                        float c  = cosT[m * 32 + dA];
                        float sn = sinT[m * 32 + dA];
                        float xA = acc[mi][nl][r] + bvA;
                        float xB = acc[mi][nl + 2][r] + bvB;
                        o[(size_t)(head * SEQLEN + m) * DKDIM + dA] = f2bf((xA * c - xB * sn) * qs);
                        o[(size_t)(head * SEQLEN + m) * DKDIM + dB] = f2bf((xB * c + xA * sn) * qs);
                    }
                }
            }
        } else {
#pragma unroll
            for (int mi = 0; mi < 4; mi++) {
#pragma unroll
                for (int ni = 0; ni < 4; ni++) {
                    int n10 = bnl * 128 + wn * 64 + ni * 16 + t15;
                    int head = n10 >> 6, dv = n10 & 63;
                    float bv = bias[n10];
                    int m = bm * 128 + wm * 64 + mi * 16 + g * 4;
                    ushort4 w4;
                    w4.x = f2bf(acc[mi][ni][0] + bv);
                    w4.y = f2bf(acc[mi][ni][1] + bv);
                    w4.z = f2bf(acc[mi][ni][2] + bv);
                    w4.w = f2bf(acc[mi][ni][3] + bv);
                    *reinterpret_cast<ushort4*>(&o2[(size_t)(head * DKDIM + dv) * SEQLEN + m]) = w4;
                }
            }
        }
    } else {
#pragma unroll
        for (int mi = 0; mi < 4; mi++) {
#pragma unroll
            for (int ni = 0; ni < 4; ni++) {
                int n = bn * 128 + wn * 64 + ni * 16 + t15;
                float bv = b0[n];
#pragma unroll
                for (int r = 0; r < 4; r++) {
                    int m = bm * 128 + wm * 64 + mi * 16 + g * 4 + r;
                    ofp[(size_t)m * DMODEL + n] = acc[mi][ni][r] + bv + resid[(size_t)m * DMODEL + n];
                }
            }
        }
    }
}

// ---------------- Flash attention: barrier-free, global-direct K/V (L2-resident) ----------------
// q (pre-scaled by log2e/8), k bf16 [head][seq][64]; vt bf16 [head][64][seq];
// out bf16 [seq][1024]. Block = 4 INDEPENDENT waves = 4 kv-chunks of the same
// 32 q-rows (block-local split-K, merged once per pass via LDS). In-wave
// pairing: pass0 = q-unit 127-p (long), pass1 = unit p (short) -> every wave
// ~16.5 kv-tiles. 1024 uniform blocks, 4/CU (LDS 36KB, VGPR<=128) = 4 waves/SIMD.
// h decoded from bid&7 so each XCD's L2 holds one head-pair (K+V = 2MB < 4MB).
__global__ __launch_bounds__(256, 4) void attn_kernel(const u16* __restrict__ q,
                                                      const u16* __restrict__ k,
                                                      const u16* __restrict__ vt,
                                                      u16* __restrict__ o) {
    __shared__ alignas(16) float Os[4][32][68];
    __shared__ float2 Ml[4][32];
    int bid = blockIdx.x;
    int xcd = bid & 7, j = bid >> 3;                 // j 0..127
    int h = xcd * 2 + (j >> 6);
    int p = j & 63;                                  // pair index
    int tid = threadIdx.x, c = tid >> 6, lane = tid & 63;
    int t15 = lane & 15, g = lane >> 4;
    const u16* Qh  = q  + (size_t)h * SEQLEN * DKDIM;
    const u16* Kh  = k  + (size_t)h * SEQLEN * DKDIM;
    const u16* VtH = vt + (size_t)h * DKDIM * SEQLEN;

    for (int pass = 0; pass < 2; pass++) {
        int u = pass ? p : (127 - p);                // 32-row q-unit
        int n = (u >> 1) + 1;                        // kv-tiles for this unit
        int kt0 = (c * n) >> 2, kt1 = ((c + 1) * n) >> 2;
        int q0 = u * 32;
        int qrowA = q0 + t15, qrowB = qrowA + 16;
        i32x4 qfA0, qfA1, qfB0, qfB1;
        {
            const u16* qp = Qh + (size_t)qrowA * DKDIM + g * 8;
            qfA0 = *reinterpret_cast<const i32x4*>(qp);
            qfA1 = *reinterpret_cast<const i32x4*>(qp + 32);
            const u16* qp2 = qp + 16 * DKDIM;
            qfB0 = *reinterpret_cast<const i32x4*>(qp2);
            qfB1 = *reinterpret_cast<const i32x4*>(qp2 + 32);
        }
        f32x4 oA[4] = {}, oB[4] = {};
        float mA = -1e30f, mB = -1e30f, lA = 0.f, lB = 0.f;

        for (int kt = kt0; kt < kt1; kt++) {
            int k0 = kt * 64;
            const u16* kp = Kh + (size_t)(k0 + t15) * DKDIM + g * 8;
            // ---- S^T = K . Q^T, K-frags direct from global (L2) ----
            f32x4 sA[4] = {}, sB[4] = {};
            __builtin_amdgcn_s_setprio(1);
#pragma unroll
            for (int kb = 0; kb < 4; kb++) {
                i32x4 kf0 = *reinterpret_cast<const i32x4*>(kp + kb * 16 * DKDIM);
                i32x4 kf1 = *reinterpret_cast<const i32x4*>(kp + kb * 16 * DKDIM + 32);
                mfma_bf16(sA[kb], kf0, qfA0);
                mfma_bf16(sA[kb], kf1, qfA1);
                mfma_bf16(sB[kb], kf0, qfB0);
                mfma_bf16(sB[kb], kf1, qfB1);
            }
            __builtin_amdgcn_s_setprio(0);
            // ---- causal mask: only the last (diagonal) tile, chunk 3 only ----
            if (kt == n - 1) {
#pragma unroll
                for (int kb = 0; kb < 4; kb++)
#pragma unroll
                    for (int r = 0; r < 4; r++) {
                        int kvg = k0 + kb * 16 + g * 4 + r;
                        if (kvg > qrowA) sA[kb][r] = -1e30f;
                        if (kvg > qrowB) sB[kb][r] = -1e30f;
                    }
            }
            // ---- per-lane tile max (tree) + defer-max (combined branch) ----
            float a0 = fmaxf(fmaxf(sA[0][0], sA[0][1]), fmaxf(sA[0][2], sA[0][3]));
            float a1 = fmaxf(fmaxf(sA[1][0], sA[1][1]), fmaxf(sA[1][2], sA[1][3]));
            float a2 = fmaxf(fmaxf(sA[2][0], sA[2][1]), fmaxf(sA[2][2], sA[2][3]));
            float a3 = fmaxf(fmaxf(sA[3][0], sA[3][1]), fmaxf(sA[3][2], sA[3][3]));
            float mxA = fmaxf(fmaxf(a0, a1), fmaxf(a2, a3));
            float b0_ = fmaxf(fmaxf(sB[0][0], sB[0][1]), fmaxf(sB[0][2], sB[0][3]));
            float b1_ = fmaxf(fmaxf(sB[1][0], sB[1][1]), fmaxf(sB[1][2], sB[1][3]));
            float b2_ = fmaxf(fmaxf(sB[2][0], sB[2][1]), fmaxf(sB[2][2], sB[2][3]));
            float b3_ = fmaxf(fmaxf(sB[3][0], sB[3][1]), fmaxf(sB[3][2], sB[3][3]));
            float mxB = fmaxf(fmaxf(b0_, b1_), fmaxf(b2_, b3_));
            if (!__all((mxA <= mA + 8.0f) && (mxB <= mB + 8.0f))) {
                float mrA = fmaxf(mxA, __shfl_xor(mxA, 16));
                mrA = fmaxf(mrA, __shfl_xor(mrA, 32));
                float mnA = fmaxf(mA, mrA);
                float fdA = exp2a(mA - mnA);
                mA = mnA; lA *= fdA;
                oA[0] *= fdA; oA[1] *= fdA; oA[2] *= fdA; oA[3] *= fdA;
                float mrB = fmaxf(mxB, __shfl_xor(mxB, 16));
                mrB = fmaxf(mrB, __shfl_xor(mrB, 32));
                float mnB = fmaxf(mB, mrB);
                float fdB = exp2a(mB - mnB);
                mB = mnB; lB *= fdB;
                oB[0] *= fdB; oB[1] *= fdB; oB[2] *= fdB; oB[3] *= fdB;
            }
            // ---- p = exp2(s - m), pack bf16 ----
            float psA = 0.f, psB = 0.f;
            u32 pwA[8], pwB[8];
#pragma unroll
            for (int kb = 0; kb < 4; kb++) {
                float pa0 = exp2a(sA[kb][0] - mA);
                float pa1 = exp2a(sA[kb][1] - mA);
                float pa2 = exp2a(sA[kb][2] - mA);
                float pa3 = exp2a(sA[kb][3] - mA);
                psA += (pa0 + pa1) + (pa2 + pa3);
                pwA[kb * 2]     = cvtpk(pa0, pa1);
                pwA[kb * 2 + 1] = cvtpk(pa2, pa3);
                float pb0 = exp2a(sB[kb][0] - mB);
                float pb1 = exp2a(sB[kb][1] - mB);
                float pb2 = exp2a(sB[kb][2] - mB);
                float pb3 = exp2a(sB[kb][3] - mB);
                psB += (pb0 + pb1) + (pb2 + pb3);
                pwB[kb * 2]     = cvtpk(pb0, pb1);
                pwB[kb * 2 + 1] = cvtpk(pb2, pb3);
            }
            lA += psA;
            lB += psB;
            // ---- O'^T += V^T . P^T, V-frags direct from global (L2) ----
            __builtin_amdgcn_s_setprio(1);
#pragma unroll
            for (int nb = 0; nb < 4; nb++) {
                const u16* vp = VtH + (size_t)(nb * 16 + t15) * SEQLEN + k0 + g * 4;
#pragma unroll
                for (int kb = 0; kb < 4; kb++) {
                    i32x2 vf = *reinterpret_cast<const i32x2*>(vp + kb * 16);
                    mfma16_bf16(oA[nb], vf, i32x2{(int)pwA[kb * 2], (int)pwA[kb * 2 + 1]});
                    mfma16_bf16(oB[nb], vf, i32x2{(int)pwB[kb * 2], (int)pwB[kb * 2 + 1]});
                }
            }
            __builtin_amdgcn_s_setprio(0);
        }
        // ---- reduce l across the 4 k-slot lanes of each q-row ----
        lA += __shfl_xor(lA, 16); lA += __shfl_xor(lA, 32);
        lB += __shfl_xor(lB, 16); lB += __shfl_xor(lB, 32);
        // ---- block-local split-K merge through LDS ----
        __syncthreads();                       // previous pass's combine done
#pragma unroll
        for (int nb = 0; nb < 4; nb++) {
            *reinterpret_cast<f32x4*>(&Os[c][t15][nb * 16 + g * 4])      = oA[nb];
            *reinterpret_cast<f32x4*>(&Os[c][t15 + 16][nb * 16 + g * 4]) = oB[nb];
        }
        if (g == 0) {
            Ml[c][t15]      = make_float2(mA, lA);
            Ml[c][t15 + 16] = make_float2(mB, lB);
        }
        __syncthreads();
        {
            int qq = tid & 31, dg = tid >> 5;          // q-row, d-group of 8
            float2 c0 = Ml[0][qq], c1 = Ml[1][qq], c2 = Ml[2][qq], c3 = Ml[3][qq];
            float M = fmaxf(fmaxf(c0.x, c1.x), fmaxf(c2.x, c3.x));
            float w0 = exp2a(c0.x - M), w1 = exp2a(c1.x - M);
            float w2 = exp2a(c2.x - M), w3 = exp2a(c3.x - M);
            float invL = 1.0f / (w0 * c0.y + w1 * c1.y + w2 * c2.y + w3 * c3.y);
            u16x8 w8;
#pragma unroll
            for (int dd = 0; dd < 8; dd++) {
                int d = dg * 8 + dd;
                float s = w0 * Os[0][qq][d] + w1 * Os[1][qq][d]
                        + w2 * Os[2][qq][d] + w3 * Os[3][qq][d];
                w8[dd] = f2bf(s * invL);
            }
            *reinterpret_cast<u16x8*>(&o[(size_t)(q0 + qq) * DMODEL + h * DKDIM + dg * 8]) = w8;
        }
    }
}

extern "C" void kernel_launch(void* const* d_in, const int* in_sizes, int n_in,
                              void* d_out, int out_size, void* d_ws, size_t ws_size,
                              hipStream_t stream) {
    const float* h     = (const float*)d_in[0];
    const float* gamma = (const float*)d_in[1];
    const float* beta  = (const float*)d_in[2];
    const float* Wq    = (const float*)d_in[3];
    const float* bq    = (const float*)d_in[4];
    const float* Wk    = (const float*)d_in[5];
    const float* bk    = (const float*)d_in[6];
    const float* Wv    = (const float*)d_in[7];
    const float* bv    = (const float*)d_in[8];
    const float* Wo    = (const float*)d_in[9];
    const float* bo    = (const float*)d_in[10];
    float* out = (float*)d_out;

    char* ws = (char*)d_ws;
    u16* hn     = (u16*)(ws);                        // 8 MiB; reused as attn output
    u16* wqkvT  = (u16*)(ws + (8ull  << 20));        // 6 MiB [3072][1024]
    u16* woT    = (u16*)(ws + (14ull << 20));        // 2 MiB
    u16* qb     = (u16*)(ws + (16ull << 20));        // [16][4096][64]
    u16* kbuf   = (u16*)(ws + (24ull << 20));        // [16][4096][64]
    u16* vtb    = (u16*)(ws + (32ull << 20));        // [16][64][4096]
    float* cosT = (float*)(ws + (40ull << 20));
    float* sinT = (float*)(ws + (40ull << 20) + (512ull << 10));
    u16* attn = hn;

    ln_kernel<<<SEQLEN, 256, 0, stream>>>(h, gamma, beta, hn);
    wconv_kernel<<<dim3(32, 32, 4), 256, 0, stream>>>(Wq, Wk, Wv, Wo, wqkvT, woT);
    rope_table_kernel<<<(SEQLEN * 32) / 256, 256, 0, stream>>>(cosT, sinT);
    gemm_kernel<0><<<dim3(32, 24), 256, 0, stream>>>(hn, wqkvT, bq, bk, bv, nullptr,
                                                     cosT, sinT, qb, kbuf, vtb, nullptr);
    attn_kernel<<<1024, 256, 0, stream>>>(qb, kbuf, vtb, attn);
    gemm_kernel<1><<<dim3(32, 8), 256, 0, stream>>>(attn, woT, bo, nullptr, nullptr, h,
                                                    nullptr, nullptr, nullptr, nullptr, nullptr, out);
}

// Round 9
// 187.278 us; speedup vs baseline: 1.3647x; 1.3647x over previous
//
#include <hip/hip_runtime.h>
#include <stdint.h>

#define SEQLEN 4096
#define DMODEL 1024
#define NHEADS 16
#define DKDIM  64

typedef unsigned short u16;
typedef unsigned int   u32;
using f32x4 = __attribute__((ext_vector_type(4))) float;
using i32x4 = __attribute__((ext_vector_type(4))) int;
using i32x2 = __attribute__((ext_vector_type(2))) int;

__device__ __forceinline__ u16 f2bf(float f) {
    u32 x = __builtin_bit_cast(u32, f);
    u32 r = x + 0x7fffu + ((x >> 16) & 1u);   // RNE
    return (u16)(r >> 16);
}
__device__ __forceinline__ float exp2a(float x) {
    float r; asm("v_exp_f32 %0, %1" : "=v"(r) : "v"(x)); return r;
}
__device__ __forceinline__ u32 cvtpk(float lo, float hi) {
    u32 r; asm("v_cvt_pk_bf16_f32 %0, %1, %2" : "=v"(r) : "v"(lo), "v"(hi)); return r;
}

// 16x16x32: A lane holds A[lane&15][(lane>>4)*8+j]; B: B[(lane>>4)*8+j][lane&15];
// C/D: D[(lane>>4)*4+r][lane&15]
__device__ __forceinline__ void mfma_bf16(f32x4& d, i32x4 a, i32x4 b) {
    asm("v_mfma_f32_16x16x32_bf16 %0, %1, %2, %0" : "+v"(d) : "v"(a), "v"(b));
}
// 16x16x16: A lane holds A[lane&15][(lane>>4)*4+j]; B: B[(lane>>4)*4+j][lane&15]
__device__ __forceinline__ void mfma16_bf16(f32x4& d, i32x2 a, i32x2 b) {
    asm("v_mfma_f32_16x16x16_bf16 %0, %1, %2, %0" : "+v"(d) : "v"(a), "v"(b));
}

// async global->LDS, 16B per lane; LDS dest = wave-uniform base + lane*16
#define ASYNC_COPY16(gsrc, ldst) \
    __builtin_amdgcn_global_load_lds((const __attribute__((address_space(1))) void*)(gsrc), \
                                     (__attribute__((address_space(3))) void*)(ldst), 16, 0, 0)

// ---------------- LayerNorm: h fp32 [4096][1024] -> hn bf16 ----------------
__global__ __launch_bounds__(256) void ln_kernel(const float* __restrict__ h,
                                                 const float* __restrict__ gamma,
                                                 const float* __restrict__ beta,
                                                 u16* __restrict__ hn) {
    int row = blockIdx.x;
    int t = threadIdx.x;
    float4 v = reinterpret_cast<const float4*>(h + (size_t)row * DMODEL)[t];
    float s  = v.x + v.y + v.z + v.w;
    float s2 = v.x*v.x + v.y*v.y + v.z*v.z + v.w*v.w;
#pragma unroll
    for (int off = 1; off < 64; off <<= 1) {
        s  += __shfl_xor(s, off);
        s2 += __shfl_xor(s2, off);
    }
    __shared__ float red[8];
    int wid = t >> 6, lane = t & 63;
    if (lane == 0) { red[wid] = s; red[4 + wid] = s2; }
    __syncthreads();
    s  = red[0] + red[1] + red[2] + red[3];
    s2 = red[4] + red[5] + red[6] + red[7];
    float mu   = s * (1.0f / DMODEL);
    float rstd = rsqrtf(s2 * (1.0f / DMODEL) - mu * mu + 1e-5f);
    float4 g = reinterpret_cast<const float4*>(gamma)[t];
    float4 b = reinterpret_cast<const float4*>(beta)[t];
    ushort4 o;
    o.x = f2bf((v.x - mu) * rstd * g.x + b.x);
    o.y = f2bf((v.y - mu) * rstd * g.y + b.y);
    o.z = f2bf((v.z - mu) * rstd * g.z + b.z);
    o.w = f2bf((v.w - mu) * rstd * g.w + b.w);
    reinterpret_cast<ushort4*>(hn + (size_t)row * DMODEL)[t] = o;
}

// ---- Weight transpose+convert (all 4 weights): W fp32 [K][N] -> Wt bf16 [N][K] ----
__global__ __launch_bounds__(256) void wconv_kernel(const float* __restrict__ Wq,
                                                    const float* __restrict__ Wk,
                                                    const float* __restrict__ Wv,
                                                    const float* __restrict__ Wo,
                                                    u16* __restrict__ wqkvT,
                                                    u16* __restrict__ woT) {
    int z = blockIdx.z;
    const float* W = (z == 0) ? Wq : (z == 1) ? Wk : (z == 2) ? Wv : Wo;
    u16* Wt = (z < 3) ? wqkvT + (size_t)z * DMODEL * DMODEL : woT;
    __shared__ float tile[32][33];
    int bx = blockIdx.x * 32;   // n
    int by = blockIdx.y * 32;   // k
    int tx = threadIdx.x & 31, ty = threadIdx.x >> 5;
#pragma unroll
    for (int i = 0; i < 32; i += 8)
        tile[ty + i][tx] = W[(size_t)(by + ty + i) * DMODEL + bx + tx];
    __syncthreads();
#pragma unroll
    for (int i = 0; i < 32; i += 8)
        Wt[(size_t)(bx + ty + i) * DMODEL + by + tx] = f2bf(tile[tx][ty + i]);
}

// ---------------- RoPE cos/sin tables: [4096][32] fp32 each ----------------
__global__ void rope_table_kernel(float* __restrict__ cosT, float* __restrict__ sinT) {
    int idx = blockIdx.x * 256 + threadIdx.x;
    int s = idx >> 5, i = idx & 31;
    float theta = powf(10000.0f, -2.0f * (float)i / 64.0f);
    float ang = (float)s * theta;
    cosT[idx] = cosf(ang);
    sinT[idx] = sinf(ang);
}

// ---------------- GEMM: 128x128 tile, BK=64, global_load_lds double-buffer ----------------
// EPI=0: merged QKV (Bt rows 0..3071). seg=bn>>3: 0=Q (RoPE, *log2e/8 -> o0),
//        1=K (RoPE -> o1), 2=V (write V^T [head][64][seq] -> o2).
// EPI=1: +bias +residual, fp32 [seq][1024] -> ofp.
template <int EPI>
__global__ __launch_bounds__(256) void gemm_kernel(const u16* __restrict__ A,
                                                   const u16* __restrict__ Bt,
                                                   const float* __restrict__ b0,
                                                   const float* __restrict__ b1,
                                                   const float* __restrict__ b2,
                                                   const float* __restrict__ resid,
                                                   const float* __restrict__ cosT,
                                                   const float* __restrict__ sinT,
                                                   u16* __restrict__ o0,
                                                   u16* __restrict__ o1,
                                                   u16* __restrict__ o2,
                                                   float* __restrict__ ofp) {
    __shared__ alignas(16) u16 As[2][128 * 64];
    __shared__ alignas(16) u16 Bs[2][128 * 64];
    int bm = blockIdx.x, bn = blockIdx.y;
    int tid = threadIdx.x;
    int wid = tid >> 6, lane = tid & 63;
    int wm = wid >> 1, wn = wid & 1;
    int t15 = lane & 15, g = lane >> 4;
    const u16* Abase = A  + (size_t)bm * 128 * DMODEL;
    const u16* Bbase = Bt + (size_t)bn * 128 * DMODEL;
    int srow = tid >> 3;          // 0..31 within each 32-row issue chunk
    int sslot = tid & 7;
    f32x4 acc[4][4] = {};

    // LDS[row][slot] = global[row][slot ^ (row&7)]  (slots of 8 elems = 16B)
#define GSTAGE(b, ks)                                                                    \
    {                                                                                    \
        _Pragma("unroll")                                                                \
        for (int i = 0; i < 4; i++) {                                                    \
            int row = i * 32 + srow;                                                     \
            int col = ((sslot ^ (row & 7)) * 8) + (ks);                                  \
            ASYNC_COPY16(Abase + (size_t)row * DMODEL + col, &As[b][i * 2048 + wid * 512]); \
            ASYNC_COPY16(Bbase + (size_t)row * DMODEL + col, &Bs[b][i * 2048 + wid * 512]); \
        }                                                                                \
    }

    GSTAGE(0, 0)
    __syncthreads();
    int buf = 0;
    for (int ks = 0; ks < DMODEL; ks += 64) {
        if (ks < DMODEL - 64) GSTAGE(buf ^ 1, ks + 64)
#pragma unroll
        for (int kk = 0; kk < 2; kk++) {
            i32x4 af[4], bfr[4];
#pragma unroll
            for (int mi = 0; mi < 4; mi++) {
                int row = wm * 64 + mi * 16 + t15;
                int sl = (kk * 4 + g) ^ (row & 7);
                af[mi] = *reinterpret_cast<const i32x4*>(&As[buf][row * 64 + sl * 8]);
            }
#pragma unroll
            for (int ni = 0; ni < 4; ni++) {
                int row = wn * 64 + ni * 16 + t15;
                int sl = (kk * 4 + g) ^ (row & 7);
                bfr[ni] = *reinterpret_cast<const i32x4*>(&Bs[buf][row * 64 + sl * 8]);
            }
            __builtin_amdgcn_s_setprio(1);
#pragma unroll
            for (int mi = 0; mi < 4; mi++)
#pragma unroll
                for (int ni = 0; ni < 4; ni++)
                    mfma_bf16(acc[mi][ni], af[mi], bfr[ni]);
            __builtin_amdgcn_s_setprio(0);
        }
        __syncthreads();
        buf ^= 1;
    }
#undef GSTAGE

    if (EPI == 0) {
        int seg = bn >> 3;                 // 0=Q 1=K 2=V
        int bnl = bn & 7;
        const float* bias = (seg == 0) ? b0 : (seg == 1) ? b1 : b2;
        if (seg < 2) {
            u16* o = (seg == 0) ? o0 : o1;
            float qs = (seg == 0) ? 0.18033688f : 1.0f;   // log2(e)/8 for Q
#pragma unroll
            for (int mi = 0; mi < 4; mi++) {
#pragma unroll
                for (int nl = 0; nl < 2; nl++) {
                    int n10 = bnl * 128 + wn * 64 + nl * 16 + t15;  // d&63 in 0..31
                    int head = n10 >> 6;
                    int dA = n10 & 63, dB = dA + 32;
                    float bvA = bias[n10], bvB = bias[n10 + 32];
#pragma unroll
                    for (int r = 0; r < 4; r++) {
                        int m = bm * 128 + wm * 64 + mi * 16 + g * 4 + r;
                        float c  = cosT[m * 32 + dA];
                        float sn = sinT[m * 32 + dA];
                        float xA = acc[mi][nl][r] + bvA;
                        float xB = acc[mi][nl + 2][r] + bvB;
                        o[(size_t)(head * SEQLEN + m) * DKDIM + dA] = f2bf((xA * c - xB * sn) * qs);
                        o[(size_t)(head * SEQLEN + m) * DKDIM + dB] = f2bf((xB * c + xA * sn) * qs);
                    }
                }
            }
        } else {
#pragma unroll
            for (int mi = 0; mi < 4; mi++) {
#pragma unroll
                for (int ni = 0; ni < 4; ni++) {
                    int n10 = bnl * 128 + wn * 64 + ni * 16 + t15;
                    int head = n10 >> 6, dv = n10 & 63;
                    float bv = bias[n10];
                    int m = bm * 128 + wm * 64 + mi * 16 + g * 4;
                    ushort4 w4;
                    w4.x = f2bf(acc[mi][ni][0] + bv);
                    w4.y = f2bf(acc[mi][ni][1] + bv);
                    w4.z = f2bf(acc[mi][ni][2] + bv);
                    w4.w = f2bf(acc[mi][ni][3] + bv);
                    *reinterpret_cast<ushort4*>(&o2[(size_t)(head * DKDIM + dv) * SEQLEN + m]) = w4;
                }
            }
        }
    } else {
#pragma unroll
        for (int mi = 0; mi < 4; mi++) {
#pragma unroll
            for (int ni = 0; ni < 4; ni++) {
                int n = bn * 128 + wn * 64 + ni * 16 + t15;
                float bv = b0[n];
#pragma unroll
                for (int r = 0; r < 4; r++) {
                    int m = bm * 128 + wm * 64 + mi * 16 + g * 4 + r;
                    ofp[(size_t)m * DMODEL + n] = acc[mi][ni][r] + bv + resid[(size_t)m * DMODEL + n];
                }
            }
        }
    }
}

// ---------------- Flash attention, causal, exp2-domain, defer-max ----------------
// q (pre-scaled by log2e/8), k bf16 [head][seq][64]; vt bf16 [head][64][seq];
// out bf16 [seq][1024]. 4 waves x 32 q-rows (two 16-row B-frags per wave) =
// 128-row Q tile. PERSISTENT blocks + dynamic task queue (atomic counter):
// task t -> (qt = 31 - t/16, head = t&15), longest-first. Balance emerges
// regardless of dispatcher block->CU mapping (r6's failure mode).
__global__ __launch_bounds__(256) void attn_kernel(const u16* __restrict__ q,
                                                   const u16* __restrict__ k,
                                                   const u16* __restrict__ vt,
                                                   u16* __restrict__ o,
                                                   u32* __restrict__ counter) {
    __shared__ alignas(16) u16 Kl[2][64 * 64];
    __shared__ alignas(16) u16 Vl[2][64 * 64];
    __shared__ int task_s;
    int tid = threadIdx.x, wid = tid >> 6, lane = tid & 63;
    int t15 = lane & 15, g = lane >> 4;
    int sslot = lane & 7;

#define STAGE(b, kt_)                                                                   \
    {                                                                                   \
        int k0s = (kt_) * 64;                                                           \
        _Pragma("unroll")                                                               \
        for (int it = 0; it < 2; it++) {                                                \
            int u   = wid * 2 + it;                                                     \
            int row = u * 8 + (lane >> 3);                                              \
            int sl  = (sslot ^ (row & 7)) * 8;                                          \
            ASYNC_COPY16(Kh + (size_t)(k0s + row) * DKDIM + sl, &Kl[b][u * 512]);       \
            ASYNC_COPY16(VtH + (size_t)row * SEQLEN + k0s + sl, &Vl[b][u * 512]);       \
        }                                                                               \
    }

    for (;;) {
        __syncthreads();                       // LDS + task_s reuse fence
        if (tid == 0) task_s = (int)atomicAdd(counter, 1u);
        __syncthreads();
        int t = task_s;
        if (t >= 32 * NHEADS) return;
        int Q = 31 - (t >> 4);                 // longest-first
        int h = t & 15;
        const u16* Qh  = q  + (size_t)h * SEQLEN * DKDIM;
        const u16* Kh  = k  + (size_t)h * SEQLEN * DKDIM;
        const u16* VtH = vt + (size_t)h * DKDIM * SEQLEN;

        int q0 = Q * 128;
        int qrowA = q0 + wid * 32 + t15;
        int qrowB = qrowA + 16;
        i32x4 qfA0, qfA1, qfB0, qfB1;
        {
            const u16* qp = Qh + (size_t)qrowA * DKDIM + g * 8;
            qfA0 = *reinterpret_cast<const i32x4*>(qp);
            qfA1 = *reinterpret_cast<const i32x4*>(qp + 32);
            const u16* qp2 = qp + 16 * DKDIM;
            qfB0 = *reinterpret_cast<const i32x4*>(qp2);
            qfB1 = *reinterpret_cast<const i32x4*>(qp2 + 32);
        }
        f32x4 oA[4] = {}, oB[4] = {};
        float mA = -1e30f, mB = -1e30f, lA = 0.f, lB = 0.f;

        STAGE(0, 0)
        __syncthreads();
        int buf = 0;
        int ktend = 2 * Q + 1;
        for (int kt = 0; kt <= ktend; kt++) {
            if (kt < ktend) STAGE(buf ^ 1, kt + 1)
            int k0 = kt * 64;
            // ---- S^T = K . Q^T for both frags (K-frags read once) ----
            f32x4 sA[4] = {}, sB[4] = {};
            __builtin_amdgcn_s_setprio(1);
#pragma unroll
            for (int kb = 0; kb < 4; kb++) {
                int j = kb * 16 + t15;
                i32x4 kf0 = *reinterpret_cast<const i32x4*>(&Kl[buf][j * 64 + ((g ^ (j & 7)) * 8)]);
                i32x4 kf1 = *reinterpret_cast<const i32x4*>(&Kl[buf][j * 64 + (((4 + g) ^ (j & 7)) * 8)]);
                mfma_bf16(sA[kb], kf0, qfA0);
                mfma_bf16(sA[kb], kf1, qfA1);
                mfma_bf16(sB[kb], kf0, qfB0);
                mfma_bf16(sB[kb], kf1, qfB1);
            }
            __builtin_amdgcn_s_setprio(0);
            // ---- causal mask: only the diagonal band (last two iterations) ----
            if (kt >= 2 * Q) {
#pragma unroll
                for (int kb = 0; kb < 4; kb++)
#pragma unroll
                    for (int r = 0; r < 4; r++) {
                        int kvg = k0 + kb * 16 + g * 4 + r;
                        if (kvg > qrowA) sA[kb][r] = -1e30f;
                        if (kvg > qrowB) sB[kb][r] = -1e30f;
                    }
            }
            // ---- per-lane tile max (tree) + defer-max (combined branch) ----
            float a0 = fmaxf(fmaxf(sA[0][0], sA[0][1]), fmaxf(sA[0][2], sA[0][3]));
            float a1 = fmaxf(fmaxf(sA[1][0], sA[1][1]), fmaxf(sA[1][2], sA[1][3]));
            float a2 = fmaxf(fmaxf(sA[2][0], sA[2][1]), fmaxf(sA[2][2], sA[2][3]));
            float a3 = fmaxf(fmaxf(sA[3][0], sA[3][1]), fmaxf(sA[3][2], sA[3][3]));
            float mxA = fmaxf(fmaxf(a0, a1), fmaxf(a2, a3));
            float b0_ = fmaxf(fmaxf(sB[0][0], sB[0][1]), fmaxf(sB[0][2], sB[0][3]));
            float b1_ = fmaxf(fmaxf(sB[1][0], sB[1][1]), fmaxf(sB[1][2], sB[1][3]));
            float b2_ = fmaxf(fmaxf(sB[2][0], sB[2][1]), fmaxf(sB[2][2], sB[2][3]));
            float b3_ = fmaxf(fmaxf(sB[3][0], sB[3][1]), fmaxf(sB[3][2], sB[3][3]));
            float mxB = fmaxf(fmaxf(b0_, b1_), fmaxf(b2_, b3_));
            if (!__all((mxA <= mA + 8.0f) && (mxB <= mB + 8.0f))) {
                float mrA = fmaxf(mxA, __shfl_xor(mxA, 16));
                mrA = fmaxf(mrA, __shfl_xor(mrA, 32));
                float mnA = fmaxf(mA, mrA);
                float fdA = exp2a(mA - mnA);
                mA = mnA; lA *= fdA;
                oA[0] *= fdA; oA[1] *= fdA; oA[2] *= fdA; oA[3] *= fdA;
                float mrB = fmaxf(mxB, __shfl_xor(mxB, 16));
                mrB = fmaxf(mrB, __shfl_xor(mrB, 32));
                float mnB = fmaxf(mB, mrB);
                float fdB = exp2a(mB - mnB);
                mB = mnB; lB *= fdB;
                oB[0] *= fdB; oB[1] *= fdB; oB[2] *= fdB; oB[3] *= fdB;
            }
            // ---- p = exp2(s - m), pack bf16 ----
            float psA = 0.f, psB = 0.f;
            u32 pwA[8], pwB[8];
#pragma unroll
            for (int kb = 0; kb < 4; kb++) {
                float pa0 = exp2a(sA[kb][0] - mA);
                float pa1 = exp2a(sA[kb][1] - mA);
                float pa2 = exp2a(sA[kb][2] - mA);
                float pa3 = exp2a(sA[kb][3] - mA);
                psA += (pa0 + pa1) + (pa2 + pa3);
                pwA[kb * 2]     = cvtpk(pa0, pa1);
                pwA[kb * 2 + 1] = cvtpk(pa2, pa3);
                float pb0 = exp2a(sB[kb][0] - mB);
                float pb1 = exp2a(sB[kb][1] - mB);
                float pb2 = exp2a(sB[kb][2] - mB);
                float pb3 = exp2a(sB[kb][3] - mB);
                psB += (pb0 + pb1) + (pb2 + pb3);
                pwB[kb * 2]     = cvtpk(pb0, pb1);
                pwB[kb * 2 + 1] = cvtpk(pb2, pb3);
            }
            lA += psA;
            lB += psB;
            // ---- O^T += V^T . P^T  (V-frags read once, feed both frags) ----
            __builtin_amdgcn_s_setprio(1);
#pragma unroll
            for (int nb = 0; nb < 4; nb++) {
                int d = nb * 16 + t15;
#pragma unroll
                for (int kb = 0; kb < 4; kb++) {
                    i32x2 vf = *reinterpret_cast<const i32x2*>(
                        &Vl[buf][d * 64 + (((kb * 2 + (g >> 1)) ^ (d & 7)) * 8) + (g & 1) * 4]);
                    mfma16_bf16(oA[nb], vf, i32x2{(int)pwA[kb * 2], (int)pwA[kb * 2 + 1]});
                    mfma16_bf16(oB[nb], vf, i32x2{(int)pwB[kb * 2], (int)pwB[kb * 2 + 1]});
                }
            }
            __builtin_amdgcn_s_setprio(0);
            __syncthreads();
            buf ^= 1;
        }
        float l0 = lA;
        l0 += __shfl_xor(l0, 16);
        l0 += __shfl_xor(l0, 32);
        float invA = 1.0f / l0;
        float l1 = lB;
        l1 += __shfl_xor(l1, 16);
        l1 += __shfl_xor(l1, 32);
        float invB = 1.0f / l1;
#pragma unroll
        for (int nb = 0; nb < 4; nb++) {
            ushort4 w4;
            w4.x = f2bf(oA[nb][0] * invA);
            w4.y = f2bf(oA[nb][1] * invA);
            w4.z = f2bf(oA[nb][2] * invA);
            w4.w = f2bf(oA[nb][3] * invA);
            *reinterpret_cast<ushort4*>(&o[(size_t)qrowA * DMODEL + h * DKDIM + nb * 16 + g * 4]) = w4;
            w4.x = f2bf(oB[nb][0] * invB);
            w4.y = f2bf(oB[nb][1] * invB);
            w4.z = f2bf(oB[nb][2] * invB);
            w4.w = f2bf(oB[nb][3] * invB);
            *reinterpret_cast<ushort4*>(&o[(size_t)qrowB * DMODEL + h * DKDIM + nb * 16 + g * 4]) = w4;
        }
    }
#undef STAGE
}

extern "C" void kernel_launch(void* const* d_in, const int* in_sizes, int n_in,
                              void* d_out, int out_size, void* d_ws, size_t ws_size,
                              hipStream_t stream) {
    const float* h     = (const float*)d_in[0];
    const float* gamma = (const float*)d_in[1];
    const float* beta  = (const float*)d_in[2];
    const float* Wq    = (const float*)d_in[3];
    const float* bq    = (const float*)d_in[4];
    const float* Wk    = (const float*)d_in[5];
    const float* bk    = (const float*)d_in[6];
    const float* Wv    = (const float*)d_in[7];
    const float* bv    = (const float*)d_in[8];
    const float* Wo    = (const float*)d_in[9];
    const float* bo    = (const float*)d_in[10];
    float* out = (float*)d_out;

    char* ws = (char*)d_ws;
    u16* hn     = (u16*)(ws);                        // 8 MiB; reused as attn output
    u16* wqkvT  = (u16*)(ws + (8ull  << 20));        // 6 MiB [3072][1024]
    u16* woT    = (u16*)(ws + (14ull << 20));        // 2 MiB
    u16* qb     = (u16*)(ws + (16ull << 20));        // [16][4096][64]
    u16* kbuf   = (u16*)(ws + (24ull << 20));        // [16][4096][64]
    u16* vtb    = (u16*)(ws + (32ull << 20));        // [16][64][4096]
    float* cosT = (float*)(ws + (40ull << 20));
    float* sinT = (float*)(ws + (40ull << 20) + (512ull << 10));
    u32* counter = (u32*)(ws + (42ull << 20));
    u16* attn = hn;

    hipMemsetAsync(counter, 0, 4, stream);
    ln_kernel<<<SEQLEN, 256, 0, stream>>>(h, gamma, beta, hn);
    wconv_kernel<<<dim3(32, 32, 4), 256, 0, stream>>>(Wq, Wk, Wv, Wo, wqkvT, woT);
    rope_table_kernel<<<(SEQLEN * 32) / 256, 256, 0, stream>>>(cosT, sinT);
    gemm_kernel<0><<<dim3(32, 24), 256, 0, stream>>>(hn, wqkvT, bq, bk, bv, nullptr,
                                                     cosT, sinT, qb, kbuf, vtb, nullptr);
    attn_kernel<<<512, 256, 0, stream>>>(qb, kbuf, vtb, attn, counter);
    gemm_kernel<1><<<dim3(32, 8), 256, 0, stream>>>(attn, woT, bo, nullptr, nullptr, h,
                                                    nullptr, nullptr, nullptr, nullptr, nullptr, out);
}

// Round 11
// 150.375 us; speedup vs baseline: 1.6996x; 1.2454x over previous
//
#include <hip/hip_runtime.h>
#include <stdint.h>

#define SEQLEN 4096
#define DMODEL 1024
#define NHEADS 16
#define DKDIM  64

typedef unsigned short u16;
typedef unsigned int   u32;
using f32x4 = __attribute__((ext_vector_type(4))) float;
using i32x4 = __attribute__((ext_vector_type(4))) int;
using i32x2 = __attribute__((ext_vector_type(2))) int;

__device__ __forceinline__ u16 f2bf(float f) {
    u32 x = __builtin_bit_cast(u32, f);
    u32 r = x + 0x7fffu + ((x >> 16) & 1u);   // RNE
    return (u16)(r >> 16);
}
__device__ __forceinline__ float exp2a(float x) {
    float r; asm("v_exp_f32 %0, %1" : "=v"(r) : "v"(x)); return r;
}
__device__ __forceinline__ u32 cvtpk(float lo, float hi) {
    u32 r; asm("v_cvt_pk_bf16_f32 %0, %1, %2" : "=v"(r) : "v"(lo), "v"(hi)); return r;
}

// 16x16x32: A lane holds A[lane&15][(lane>>4)*8+j]; B: B[(lane>>4)*8+j][lane&15];
// C/D: D[(lane>>4)*4+r][lane&15]
__device__ __forceinline__ void mfma_bf16(f32x4& d, i32x4 a, i32x4 b) {
    asm("v_mfma_f32_16x16x32_bf16 %0, %1, %2, %0" : "+v"(d) : "v"(a), "v"(b));
}
// 16x16x16: A lane holds A[lane&15][(lane>>4)*4+j]; B: B[(lane>>4)*4+j][lane&15]
__device__ __forceinline__ void mfma16_bf16(f32x4& d, i32x2 a, i32x2 b) {
    asm("v_mfma_f32_16x16x16_bf16 %0, %1, %2, %0" : "+v"(d) : "v"(a), "v"(b));
}

// async global->LDS, 16B per lane; LDS dest = wave-uniform base + lane*16
#define ASYNC_COPY16(gsrc, ldst) \
    __builtin_amdgcn_global_load_lds((const __attribute__((address_space(1))) void*)(gsrc), \
                                     (__attribute__((address_space(3))) void*)(ldst), 16, 0, 0)

// ---------------- LayerNorm: h fp32 [4096][1024] -> hn bf16 ----------------
__global__ __launch_bounds__(256) void ln_kernel(const float* __restrict__ h,
                                                 const float* __restrict__ gamma,
                                                 const float* __restrict__ beta,
                                                 u16* __restrict__ hn) {
    int row = blockIdx.x;
    int t = threadIdx.x;
    float4 v = reinterpret_cast<const float4*>(h + (size_t)row * DMODEL)[t];
    float s  = v.x + v.y + v.z + v.w;
    float s2 = v.x*v.x + v.y*v.y + v.z*v.z + v.w*v.w;
#pragma unroll
    for (int off = 1; off < 64; off <<= 1) {
        s  += __shfl_xor(s, off);
        s2 += __shfl_xor(s2, off);
    }
    __shared__ float red[8];
    int wid = t >> 6, lane = t & 63;
    if (lane == 0) { red[wid] = s; red[4 + wid] = s2; }
    __syncthreads();
    s  = red[0] + red[1] + red[2] + red[3];
    s2 = red[4] + red[5] + red[6] + red[7];
    float mu   = s * (1.0f / DMODEL);
    float rstd = rsqrtf(s2 * (1.0f / DMODEL) - mu * mu + 1e-5f);
    float4 g = reinterpret_cast<const float4*>(gamma)[t];
    float4 b = reinterpret_cast<const float4*>(beta)[t];
    ushort4 o;
    o.x = f2bf((v.x - mu) * rstd * g.x + b.x);
    o.y = f2bf((v.y - mu) * rstd * g.y + b.y);
    o.z = f2bf((v.z - mu) * rstd * g.z + b.z);
    o.w = f2bf((v.w - mu) * rstd * g.w + b.w);
    reinterpret_cast<ushort4*>(hn + (size_t)row * DMODEL)[t] = o;
}

// ---- Weight transpose+convert (all 4 weights): W fp32 [K][N] -> Wt bf16 [N][K] ----
__global__ __launch_bounds__(256) void wconv_kernel(const float* __restrict__ Wq,
                                                    const float* __restrict__ Wk,
                                                    const float* __restrict__ Wv,
                                                    const float* __restrict__ Wo,
                                                    u16* __restrict__ wqkvT,
                                                    u16* __restrict__ woT) {
    int z = blockIdx.z;
    const float* W = (z == 0) ? Wq : (z == 1) ? Wk : (z == 2) ? Wv : Wo;
    u16* Wt = (z < 3) ? wqkvT + (size_t)z * DMODEL * DMODEL : woT;
    __shared__ float tile[32][33];
    int bx = blockIdx.x * 32;   // n
    int by = blockIdx.y * 32;   // k
    int tx = threadIdx.x & 31, ty = threadIdx.x >> 5;
#pragma unroll
    for (int i = 0; i < 32; i += 8)
        tile[ty + i][tx] = W[(size_t)(by + ty + i) * DMODEL + bx + tx];
    __syncthreads();
#pragma unroll
    for (int i = 0; i < 32; i += 8)
        Wt[(size_t)(bx + ty + i) * DMODEL + by + tx] = f2bf(tile[tx][ty + i]);
}

// ---------------- RoPE cos/sin tables: [4096][32] fp32 each ----------------
__global__ void rope_table_kernel(float* __restrict__ cosT, float* __restrict__ sinT) {
    int idx = blockIdx.x * 256 + threadIdx.x;
    int s = idx >> 5, i = idx & 31;
    float theta = powf(10000.0f, -2.0f * (float)i / 64.0f);
    float ang = (float)s * theta;
    cosT[idx] = cosf(ang);
    sinT[idx] = sinf(ang);
}

// ---------------- GEMM: 128x128 tile, BK=64, global_load_lds double-buffer ----------------
// EPI=0: merged QKV (Bt rows 0..3071). seg=bn>>3: 0=Q (RoPE, *log2e/8 -> o0),
//        1=K (RoPE -> o1), 2=V (write V^T [head][64][seq] -> o2).
// EPI=1: +bias +residual, fp32 [seq][1024] -> ofp.
template <int EPI>
__global__ __launch_bounds__(256) void gemm_kernel(const u16* __restrict__ A,
                                                   const u16* __restrict__ Bt,
                                                   const float* __restrict__ b0,
                                                   const float* __restrict__ b1,
                                                   const float* __restrict__ b2,
                                                   const float* __restrict__ resid,
                                                   const float* __restrict__ cosT,
                                                   const float* __restrict__ sinT,
                                                   u16* __restrict__ o0,
                                                   u16* __restrict__ o1,
                                                   u16* __restrict__ o2,
                                                   float* __restrict__ ofp) {
    __shared__ alignas(16) u16 As[2][128 * 64];
    __shared__ alignas(16) u16 Bs[2][128 * 64];
    int bm = blockIdx.x, bn = blockIdx.y;
    int tid = threadIdx.x;
    int wid = tid >> 6, lane = tid & 63;
    int wm = wid >> 1, wn = wid & 1;
    int t15 = lane & 15, g = lane >> 4;
    const u16* Abase = A  + (size_t)bm * 128 * DMODEL;
    const u16* Bbase = Bt + (size_t)bn * 128 * DMODEL;
    int srow = tid >> 3;          // 0..31 within each 32-row issue chunk
    int sslot = tid & 7;
    f32x4 acc[4][4] = {};

    // LDS[row][slot] = global[row][slot ^ (row&7)]  (slots of 8 elems = 16B)
#define GSTAGE(b, ks)                                                                    \
    {                                                                                    \
        _Pragma("unroll")                                                                \
        for (int i = 0; i < 4; i++) {                                                    \
            int row = i * 32 + srow;                                                     \
            int col = ((sslot ^ (row & 7)) * 8) + (ks);                                  \
            ASYNC_COPY16(Abase + (size_t)row * DMODEL + col, &As[b][i * 2048 + wid * 512]); \
            ASYNC_COPY16(Bbase + (size_t)row * DMODEL + col, &Bs[b][i * 2048 + wid * 512]); \
        }                                                                                \
    }

    GSTAGE(0, 0)
    __syncthreads();
    int buf = 0;
    for (int ks = 0; ks < DMODEL; ks += 64) {
        if (ks < DMODEL - 64) GSTAGE(buf ^ 1, ks + 64)
#pragma unroll
        for (int kk = 0; kk < 2; kk++) {
            i32x4 af[4], bfr[4];
#pragma unroll
            for (int mi = 0; mi < 4; mi++) {
                int row = wm * 64 + mi * 16 + t15;
                int sl = (kk * 4 + g) ^ (row & 7);
                af[mi] = *reinterpret_cast<const i32x4*>(&As[buf][row * 64 + sl * 8]);
            }
#pragma unroll
            for (int ni = 0; ni < 4; ni++) {
                int row = wn * 64 + ni * 16 + t15;
                int sl = (kk * 4 + g) ^ (row & 7);
                bfr[ni] = *reinterpret_cast<const i32x4*>(&Bs[buf][row * 64 + sl * 8]);
            }
            __builtin_amdgcn_s_setprio(1);
#pragma unroll
            for (int mi = 0; mi < 4; mi++)
#pragma unroll
                for (int ni = 0; ni < 4; ni++)
                    mfma_bf16(acc[mi][ni], af[mi], bfr[ni]);
            __builtin_amdgcn_s_setprio(0);
        }
        __syncthreads();
        buf ^= 1;
    }
#undef GSTAGE

    if (EPI == 0) {
        int seg = bn >> 3;                 // 0=Q 1=K 2=V
        int bnl = bn & 7;
        const float* bias = (seg == 0) ? b0 : (seg == 1) ? b1 : b2;
        if (seg < 2) {
            u16* o = (seg == 0) ? o0 : o1;
            float qs = (seg == 0) ? 0.18033688f : 1.0f;   // log2(e)/8 for Q
#pragma unroll
            for (int mi = 0; mi < 4; mi++) {
#pragma unroll
                for (int nl = 0; nl < 2; nl++) {
                    int n10 = bnl * 128 + wn * 64 + nl * 16 + t15;  // d&63 in 0..31
                    int head = n10 >> 6;
                    int dA = n10 & 63, dB = dA + 32;
                    float bvA = bias[n10], bvB = bias[n10 + 32];
#pragma unroll
                    for (int r = 0; r < 4; r++) {
                        int m = bm * 128 + wm * 64 + mi * 16 + g * 4 + r;
                        float c  = cosT[m * 32 + dA];
                        float sn = sinT[m * 32 + dA];
                        float xA = acc[mi][nl][r] + bvA;
                        float xB = acc[mi][nl + 2][r] + bvB;
                        o[(size_t)(head * SEQLEN + m) * DKDIM + dA] = f2bf((xA * c - xB * sn) * qs);
                        o[(size_t)(head * SEQLEN + m) * DKDIM + dB] = f2bf((xB * c + xA * sn) * qs);
                    }
                }
            }
        } else {
#pragma unroll
            for (int mi = 0; mi < 4; mi++) {
#pragma unroll
                for (int ni = 0; ni < 4; ni++) {
                    int n10 = bnl * 128 + wn * 64 + ni * 16 + t15;
                    int head = n10 >> 6, dv = n10 & 63;
                    float bv = bias[n10];
                    int m = bm * 128 + wm * 64 + mi * 16 + g * 4;
                    ushort4 w4;
                    w4.x = f2bf(acc[mi][ni][0] + bv);
                    w4.y = f2bf(acc[mi][ni][1] + bv);
                    w4.z = f2bf(acc[mi][ni][2] + bv);
                    w4.w = f2bf(acc[mi][ni][3] + bv);
                    *reinterpret_cast<ushort4*>(&o2[(size_t)(head * DKDIM + dv) * SEQLEN + m]) = w4;
                }
            }
        }
    } else {
#pragma unroll
        for (int mi = 0; mi < 4; mi++) {
#pragma unroll
            for (int ni = 0; ni < 4; ni++) {
                int n = bn * 128 + wn * 64 + ni * 16 + t15;
                float bv = b0[n];
#pragma unroll
                for (int r = 0; r < 4; r++) {
                    int m = bm * 128 + wm * 64 + mi * 16 + g * 4 + r;
                    ofp[(size_t)m * DMODEL + n] = acc[mi][ni][r] + bv + resid[(size_t)m * DMODEL + n];
                }
            }
        }
    }
}

// ---------------- Flash attention, causal, exp2-domain, defer-max ----------------
// q (pre-scaled by log2e/8), k bf16 [head][seq][64]; vt bf16 [head][64][seq];
// out bf16 [seq][1024]. r4 sync structure (double buffer + __syncthreads) with
// KVBLK=128: 4 waves x 16 q-rows = 64-row Q tile; KV tiles of 128 rows halve
// the drain count (33 uniform iterations/block via triangle pairing p,63-p).
__global__ __launch_bounds__(256, 2) void attn_kernel(const u16* __restrict__ q,
                                                      const u16* __restrict__ k,
                                                      const u16* __restrict__ vt,
                                                      u16* __restrict__ o) {
    __shared__ alignas(16) u16 Kl[2][128 * 64];   // [kv-row][d]
    __shared__ alignas(16) u16 Vl[2][64 * 128];   // [d][kv-col]
    int h = blockIdx.y;
    int p = blockIdx.x;                              // 0..31
    int tid = threadIdx.x, wid = tid >> 6, lane = tid & 63;
    int t15 = lane & 15, g = lane >> 4;
    const u16* Qh  = q  + (size_t)h * SEQLEN * DKDIM;
    const u16* Kh  = k  + (size_t)h * SEQLEN * DKDIM;
    const u16* VtH = vt + (size_t)h * DKDIM * SEQLEN;
    int sslotK = lane & 7;                           // K: 8 slots/row
    int sslotV = lane & 15;                          // V: 16 slots/row

    // stage 128-row K tile + 64x128 V^T tile; 8 loads/wave, linear LDS dest,
    // pre-swizzled global source (slot ^= row&7 on 16B slots)
#define STAGE(b, kt_)                                                                   \
    {                                                                                   \
        int k0s = (kt_) * 128;                                                          \
        _Pragma("unroll")                                                               \
        for (int it = 0; it < 4; it++) {                                                \
            int u    = wid * 4 + it;                 /* 0..15 */                        \
            int krow = u * 8 + (lane >> 3);          /* 0..127 */                       \
            int ksl  = (sslotK ^ (krow & 7)) * 8;                                       \
            ASYNC_COPY16(Kh + (size_t)(k0s + krow) * DKDIM + ksl, &Kl[b][u * 512]);     \
            int vrow = u * 4 + (lane >> 4);          /* 0..63 */                        \
            int vsl  = (sslotV ^ (vrow & 7)) * 8;                                       \
            ASYNC_COPY16(VtH + (size_t)vrow * SEQLEN + k0s + vsl, &Vl[b][u * 512]);     \
        }                                                                               \
    }

    for (int pass = 0; pass < 2; pass++) {
        int qt = pass ? p : (63 - p);                // 64-row q-tile index
        int n = (qt + 2) >> 1;                       // 128-row kv-tiles needed
        int q0 = qt * 64;
        int qrow = q0 + wid * 16 + t15;
        i32x4 qf0, qf1;
        {
            const u16* qp = Qh + (size_t)qrow * DKDIM + g * 8;
            qf0 = *reinterpret_cast<const i32x4*>(qp);
            qf1 = *reinterpret_cast<const i32x4*>(qp + 32);
        }
        f32x4 oacc[4] = {};
        float m_run = -1e30f, l_part = 0.f;

        STAGE(0, 0)
        __syncthreads();
        int buf = 0;
        for (int kt = 0; kt < n; kt++) {
            if (kt + 1 < n) STAGE(buf ^ 1, kt + 1)
            int k0 = kt * 128;
            // ---- S^T = K . Q^T  (exp2 domain via Q prescale), 8 kv-16 blocks ----
            f32x4 sacc[8] = {};
            __builtin_amdgcn_s_setprio(1);
#pragma unroll
            for (int kb = 0; kb < 8; kb++) {
                int j = kb * 16 + t15;
                i32x4 kf0 = *reinterpret_cast<const i32x4*>(&Kl[buf][j * 64 + ((g ^ (j & 7)) * 8)]);
                i32x4 kf1 = *reinterpret_cast<const i32x4*>(&Kl[buf][j * 64 + (((4 + g) ^ (j & 7)) * 8)]);
                mfma_bf16(sacc[kb], kf0, qf0);
                mfma_bf16(sacc[kb], kf1, qf1);
            }
            __builtin_amdgcn_s_setprio(0);
            // ---- causal mask: only the last tile of the pass ----
            if (kt == n - 1) {
#pragma unroll
                for (int kb = 0; kb < 8; kb++)
#pragma unroll
                    for (int r = 0; r < 4; r++) {
                        int kvg = k0 + kb * 16 + g * 4 + r;
                        if (kvg > qrow) sacc[kb][r] = -1e30f;
                    }
            }
            // ---- per-lane tile max (tree) + defer-max ----
            float a0 = fmaxf(fmaxf(sacc[0][0], sacc[0][1]), fmaxf(sacc[0][2], sacc[0][3]));
            float a1 = fmaxf(fmaxf(sacc[1][0], sacc[1][1]), fmaxf(sacc[1][2], sacc[1][3]));
            float a2 = fmaxf(fmaxf(sacc[2][0], sacc[2][1]), fmaxf(sacc[2][2], sacc[2][3]));
            float a3 = fmaxf(fmaxf(sacc[3][0], sacc[3][1]), fmaxf(sacc[3][2], sacc[3][3]));
            float a4 = fmaxf(fmaxf(sacc[4][0], sacc[4][1]), fmaxf(sacc[4][2], sacc[4][3]));
            float a5 = fmaxf(fmaxf(sacc[5][0], sacc[5][1]), fmaxf(sacc[5][2], sacc[5][3]));
            float a6 = fmaxf(fmaxf(sacc[6][0], sacc[6][1]), fmaxf(sacc[6][2], sacc[6][3]));
            float a7 = fmaxf(fmaxf(sacc[7][0], sacc[7][1]), fmaxf(sacc[7][2], sacc[7][3]));
            float mx = fmaxf(fmaxf(fmaxf(a0, a1), fmaxf(a2, a3)),
                             fmaxf(fmaxf(a4, a5), fmaxf(a6, a7)));
            if (!__all(mx <= m_run + 8.0f)) {
                float mrow = fmaxf(mx, __shfl_xor(mx, 16));
                mrow = fmaxf(mrow, __shfl_xor(mrow, 32));
                float mnew = fmaxf(m_run, mrow);
                float fold = exp2a(m_run - mnew);
                m_run = mnew;
                l_part *= fold;
                oacc[0] *= fold; oacc[1] *= fold; oacc[2] *= fold; oacc[3] *= fold;
            }
            // ---- p = exp2(s - m), pack bf16 ----
            float ps = 0.f;
            u32 pw[16];
#pragma unroll
            for (int kb = 0; kb < 8; kb++) {
                float p0 = exp2a(sacc[kb][0] - m_run);
                float p1 = exp2a(sacc[kb][1] - m_run);
                float p2 = exp2a(sacc[kb][2] - m_run);
                float p3 = exp2a(sacc[kb][3] - m_run);
                ps += (p0 + p1) + (p2 + p3);
                pw[kb * 2]     = cvtpk(p0, p1);
                pw[kb * 2 + 1] = cvtpk(p2, p3);
            }
            l_part += ps;
            // ---- O^T += V^T . P^T  (16x16x16, P in B-layout) ----
            __builtin_amdgcn_s_setprio(1);
#pragma unroll
            for (int nb = 0; nb < 4; nb++) {
                int d = nb * 16 + t15;
#pragma unroll
                for (int kb = 0; kb < 8; kb++) {
                    i32x2 vf = *reinterpret_cast<const i32x2*>(
                        &Vl[buf][d * 128 + (((kb * 2 + (g >> 1)) ^ (d & 7)) * 8) + (g & 1) * 4]);
                    i32x2 pf = i32x2{(int)pw[kb * 2], (int)pw[kb * 2 + 1]};
                    mfma16_bf16(oacc[nb], vf, pf);
                }
            }
            __builtin_amdgcn_s_setprio(0);
            __syncthreads();
            buf ^= 1;
        }
        float l = l_part;
        l += __shfl_xor(l, 16);
        l += __shfl_xor(l, 32);
        float inv_l = 1.0f / l;
#pragma unroll
        for (int nb = 0; nb < 4; nb++) {
            ushort4 w4;
            w4.x = f2bf(oacc[nb][0] * inv_l);
            w4.y = f2bf(oacc[nb][1] * inv_l);
            w4.z = f2bf(oacc[nb][2] * inv_l);
            w4.w = f2bf(oacc[nb][3] * inv_l);
            *reinterpret_cast<ushort4*>(&o[(size_t)qrow * DMODEL + h * DKDIM + nb * 16 + g * 4]) = w4;
        }
        __syncthreads();   // protect K/V buffers before next pass's prologue stage
    }
#undef STAGE
}

extern "C" void kernel_launch(void* const* d_in, const int* in_sizes, int n_in,
                              void* d_out, int out_size, void* d_ws, size_t ws_size,
                              hipStream_t stream) {
    const float* h     = (const float*)d_in[0];
    const float* gamma = (const float*)d_in[1];
    const float* beta  = (const float*)d_in[2];
    const float* Wq    = (const float*)d_in[3];
    const float* bq    = (const float*)d_in[4];
    const float* Wk    = (const float*)d_in[5];
    const float* bk    = (const float*)d_in[6];
    const float* Wv    = (const float*)d_in[7];
    const float* bv    = (const float*)d_in[8];
    const float* Wo    = (const float*)d_in[9];
    const float* bo    = (const float*)d_in[10];
    float* out = (float*)d_out;

    char* ws = (char*)d_ws;
    u16* hn     = (u16*)(ws);                        // 8 MiB; reused as attn output
    u16* wqkvT  = (u16*)(ws + (8ull  << 20));        // 6 MiB [3072][1024]
    u16* woT    = (u16*)(ws + (14ull << 20));        // 2 MiB
    u16* qb     = (u16*)(ws + (16ull << 20));        // [16][4096][64]
    u16* kbuf   = (u16*)(ws + (24ull << 20));        // [16][4096][64]
    u16* vtb    = (u16*)(ws + (32ull << 20));        // [16][64][4096]
    float* cosT = (float*)(ws + (40ull << 20));
    float* sinT = (float*)(ws + (40ull << 20) + (512ull << 10));
    u16* attn = hn;

    ln_kernel<<<SEQLEN, 256, 0, stream>>>(h, gamma, beta, hn);
    wconv_kernel<<<dim3(32, 32, 4), 256, 0, stream>>>(Wq, Wk, Wv, Wo, wqkvT, woT);
    rope_table_kernel<<<(SEQLEN * 32) / 256, 256, 0, stream>>>(cosT, sinT);
    gemm_kernel<0><<<dim3(32, 24), 256, 0, stream>>>(hn, wqkvT, bq, bk, bv, nullptr,
                                                     cosT, sinT, qb, kbuf, vtb, nullptr);
    dim3 agrid(32, NHEADS);
    attn_kernel<<<agrid, 256, 0, stream>>>(qb, kbuf, vtb, attn);
    gemm_kernel<1><<<dim3(32, 8), 256, 0, stream>>>(attn, woT, bo, nullptr, nullptr, h,
                                                    nullptr, nullptr, nullptr, nullptr, nullptr, out);
}

// Round 12
// 143.765 us; speedup vs baseline: 1.7777x; 1.0460x over previous
//
#include <hip/hip_runtime.h>
#include <stdint.h>

#define SEQLEN 4096
#define DMODEL 1024
#define NHEADS 16
#define DKDIM  64

typedef unsigned short u16;
typedef unsigned int   u32;
using f32x4 = __attribute__((ext_vector_type(4))) float;
using i32x4 = __attribute__((ext_vector_type(4))) int;
using i32x2 = __attribute__((ext_vector_type(2))) int;

__device__ __forceinline__ u16 f2bf(float f) {
    u32 x = __builtin_bit_cast(u32, f);
    u32 r = x + 0x7fffu + ((x >> 16) & 1u);   // RNE
    return (u16)(r >> 16);
}
__device__ __forceinline__ float exp2a(float x) {
    float r; asm("v_exp_f32 %0, %1" : "=v"(r) : "v"(x)); return r;
}
__device__ __forceinline__ u32 cvtpk(float lo, float hi) {
    u32 r; asm("v_cvt_pk_bf16_f32 %0, %1, %2" : "=v"(r) : "v"(lo), "v"(hi)); return r;
}

// 16x16x32: A lane holds A[lane&15][(lane>>4)*8+j]; B: B[(lane>>4)*8+j][lane&15];
// C/D: D[(lane>>4)*4+r][lane&15]
__device__ __forceinline__ void mfma_bf16(f32x4& d, i32x4 a, i32x4 b) {
    asm("v_mfma_f32_16x16x32_bf16 %0, %1, %2, %0" : "+v"(d) : "v"(a), "v"(b));
}
// 16x16x16: A lane holds A[lane&15][(lane>>4)*4+j]; B: B[(lane>>4)*4+j][lane&15]
__device__ __forceinline__ void mfma16_bf16(f32x4& d, i32x2 a, i32x2 b) {
    asm("v_mfma_f32_16x16x16_bf16 %0, %1, %2, %0" : "+v"(d) : "v"(a), "v"(b));
}

// async global->LDS, 16B per lane; LDS dest = wave-uniform base + lane*16
#define ASYNC_COPY16(gsrc, ldst) \
    __builtin_amdgcn_global_load_lds((const __attribute__((address_space(1))) void*)(gsrc), \
                                     (__attribute__((address_space(3))) void*)(ldst), 16, 0, 0)

// ---------------- LayerNorm: h fp32 [4096][1024] -> hn bf16 ----------------
__global__ __launch_bounds__(256) void ln_kernel(const float* __restrict__ h,
                                                 const float* __restrict__ gamma,
                                                 const float* __restrict__ beta,
                                                 u16* __restrict__ hn) {
    int row = blockIdx.x;
    int t = threadIdx.x;
    float4 v = reinterpret_cast<const float4*>(h + (size_t)row * DMODEL)[t];
    float s  = v.x + v.y + v.z + v.w;
    float s2 = v.x*v.x + v.y*v.y + v.z*v.z + v.w*v.w;
#pragma unroll
    for (int off = 1; off < 64; off <<= 1) {
        s  += __shfl_xor(s, off);
        s2 += __shfl_xor(s2, off);
    }
    __shared__ float red[8];
    int wid = t >> 6, lane = t & 63;
    if (lane == 0) { red[wid] = s; red[4 + wid] = s2; }
    __syncthreads();
    s  = red[0] + red[1] + red[2] + red[3];
    s2 = red[4] + red[5] + red[6] + red[7];
    float mu   = s * (1.0f / DMODEL);
    float rstd = rsqrtf(s2 * (1.0f / DMODEL) - mu * mu + 1e-5f);
    float4 g = reinterpret_cast<const float4*>(gamma)[t];
    float4 b = reinterpret_cast<const float4*>(beta)[t];
    ushort4 o;
    o.x = f2bf((v.x - mu) * rstd * g.x + b.x);
    o.y = f2bf((v.y - mu) * rstd * g.y + b.y);
    o.z = f2bf((v.z - mu) * rstd * g.z + b.z);
    o.w = f2bf((v.w - mu) * rstd * g.w + b.w);
    reinterpret_cast<ushort4*>(hn + (size_t)row * DMODEL)[t] = o;
}

// ---- Weight transpose+convert (all 4 weights): W fp32 [K][N] -> Wt bf16 [N][K] ----
__global__ __launch_bounds__(256) void wconv_kernel(const float* __restrict__ Wq,
                                                    const float* __restrict__ Wk,
                                                    const float* __restrict__ Wv,
                                                    const float* __restrict__ Wo,
                                                    u16* __restrict__ wqkvT,
                                                    u16* __restrict__ woT) {
    int z = blockIdx.z;
    const float* W = (z == 0) ? Wq : (z == 1) ? Wk : (z == 2) ? Wv : Wo;
    u16* Wt = (z < 3) ? wqkvT + (size_t)z * DMODEL * DMODEL : woT;
    __shared__ float tile[32][33];
    int bx = blockIdx.x * 32;   // n
    int by = blockIdx.y * 32;   // k
    int tx = threadIdx.x & 31, ty = threadIdx.x >> 5;
#pragma unroll
    for (int i = 0; i < 32; i += 8)
        tile[ty + i][tx] = W[(size_t)(by + ty + i) * DMODEL + bx + tx];
    __syncthreads();
#pragma unroll
    for (int i = 0; i < 32; i += 8)
        Wt[(size_t)(bx + ty + i) * DMODEL + by + tx] = f2bf(tile[tx][ty + i]);
}

// ---------------- RoPE cos/sin tables: [4096][32] fp32 each ----------------
__global__ void rope_table_kernel(float* __restrict__ cosT, float* __restrict__ sinT) {
    int idx = blockIdx.x * 256 + threadIdx.x;
    int s = idx >> 5, i = idx & 31;
    float theta = powf(10000.0f, -2.0f * (float)i / 64.0f);
    float ang = (float)s * theta;
    cosT[idx] = cosf(ang);
    sinT[idx] = sinf(ang);
}

// ---------------- GEMM: 128x128 tile, BK=64, global_load_lds double-buffer ----------------
// EPI=0: merged QKV (Bt rows 0..3071). seg=bn>>3: 0=Q (RoPE, *log2e/8 -> o0),
//        1=K (RoPE -> o1), 2=V (write V^T [head][64][seq] -> o2).
// EPI=1: +bias +residual, fp32 [seq][1024] -> ofp.
template <int EPI>
__global__ __launch_bounds__(256) void gemm_kernel(const u16* __restrict__ A,
                                                   const u16* __restrict__ Bt,
                                                   const float* __restrict__ b0,
                                                   const float* __restrict__ b1,
                                                   const float* __restrict__ b2,
                                                   const float* __restrict__ resid,
                                                   const float* __restrict__ cosT,
                                                   const float* __restrict__ sinT,
                                                   u16* __restrict__ o0,
                                                   u16* __restrict__ o1,
                                                   u16* __restrict__ o2,
                                                   float* __restrict__ ofp) {
    __shared__ alignas(16) u16 As[2][128 * 64];
    __shared__ alignas(16) u16 Bs[2][128 * 64];
    int bm = blockIdx.x, bn = blockIdx.y;
    int tid = threadIdx.x;
    int wid = tid >> 6, lane = tid & 63;
    int wm = wid >> 1, wn = wid & 1;
    int t15 = lane & 15, g = lane >> 4;
    const u16* Abase = A  + (size_t)bm * 128 * DMODEL;
    const u16* Bbase = Bt + (size_t)bn * 128 * DMODEL;
    int srow = tid >> 3;          // 0..31 within each 32-row issue chunk
    int sslot = tid & 7;
    f32x4 acc[4][4] = {};

    // LDS[row][slot] = global[row][slot ^ (row&7)]  (slots of 8 elems = 16B)
#define GSTAGE(b, ks)                                                                    \
    {                                                                                    \
        _Pragma("unroll")                                                                \
        for (int i = 0; i < 4; i++) {                                                    \
            int row = i * 32 + srow;                                                     \
            int col = ((sslot ^ (row & 7)) * 8) + (ks);                                  \
            ASYNC_COPY16(Abase + (size_t)row * DMODEL + col, &As[b][i * 2048 + wid * 512]); \
            ASYNC_COPY16(Bbase + (size_t)row * DMODEL + col, &Bs[b][i * 2048 + wid * 512]); \
        }                                                                                \
    }

    GSTAGE(0, 0)
    __syncthreads();
    int buf = 0;
    for (int ks = 0; ks < DMODEL; ks += 64) {
        if (ks < DMODEL - 64) GSTAGE(buf ^ 1, ks + 64)
#pragma unroll
        for (int kk = 0; kk < 2; kk++) {
            i32x4 af[4], bfr[4];
#pragma unroll
            for (int mi = 0; mi < 4; mi++) {
                int row = wm * 64 + mi * 16 + t15;
                int sl = (kk * 4 + g) ^ (row & 7);
                af[mi] = *reinterpret_cast<const i32x4*>(&As[buf][row * 64 + sl * 8]);
            }
#pragma unroll
            for (int ni = 0; ni < 4; ni++) {
                int row = wn * 64 + ni * 16 + t15;
                int sl = (kk * 4 + g) ^ (row & 7);
                bfr[ni] = *reinterpret_cast<const i32x4*>(&Bs[buf][row * 64 + sl * 8]);
            }
            __builtin_amdgcn_s_setprio(1);
#pragma unroll
            for (int mi = 0; mi < 4; mi++)
#pragma unroll
                for (int ni = 0; ni < 4; ni++)
                    mfma_bf16(acc[mi][ni], af[mi], bfr[ni]);
            __builtin_amdgcn_s_setprio(0);
        }
        __syncthreads();
        buf ^= 1;
    }
#undef GSTAGE

    if (EPI == 0) {
        int seg = bn >> 3;                 // 0=Q 1=K 2=V
        int bnl = bn & 7;
        const float* bias = (seg == 0) ? b0 : (seg == 1) ? b1 : b2;
        if (seg < 2) {
            u16* o = (seg == 0) ? o0 : o1;
            float qs = (seg == 0) ? 0.18033688f : 1.0f;   // log2(e)/8 for Q
#pragma unroll
            for (int mi = 0; mi < 4; mi++) {
#pragma unroll
                for (int nl = 0; nl < 2; nl++) {
                    int n10 = bnl * 128 + wn * 64 + nl * 16 + t15;  // d&63 in 0..31
                    int head = n10 >> 6;
                    int dA = n10 & 63, dB = dA + 32;
                    float bvA = bias[n10], bvB = bias[n10 + 32];
#pragma unroll
                    for (int r = 0; r < 4; r++) {
                        int m = bm * 128 + wm * 64 + mi * 16 + g * 4 + r;
                        float c  = cosT[m * 32 + dA];
                        float sn = sinT[m * 32 + dA];
                        float xA = acc[mi][nl][r] + bvA;
                        float xB = acc[mi][nl + 2][r] + bvB;
                        o[(size_t)(head * SEQLEN + m) * DKDIM + dA] = f2bf((xA * c - xB * sn) * qs);
                        o[(size_t)(head * SEQLEN + m) * DKDIM + dB] = f2bf((xB * c + xA * sn) * qs);
                    }
                }
            }
        } else {
#pragma unroll
            for (int mi = 0; mi < 4; mi++) {
#pragma unroll
                for (int ni = 0; ni < 4; ni++) {
                    int n10 = bnl * 128 + wn * 64 + ni * 16 + t15;
                    int head = n10 >> 6, dv = n10 & 63;
                    float bv = bias[n10];
                    int m = bm * 128 + wm * 64 + mi * 16 + g * 4;
                    ushort4 w4;
                    w4.x = f2bf(acc[mi][ni][0] + bv);
                    w4.y = f2bf(acc[mi][ni][1] + bv);
                    w4.z = f2bf(acc[mi][ni][2] + bv);
                    w4.w = f2bf(acc[mi][ni][3] + bv);
                    *reinterpret_cast<ushort4*>(&o2[(size_t)(head * DKDIM + dv) * SEQLEN + m]) = w4;
                }
            }
        }
    } else {
#pragma unroll
        for (int mi = 0; mi < 4; mi++) {
#pragma unroll
            for (int ni = 0; ni < 4; ni++) {
                int n = bn * 128 + wn * 64 + ni * 16 + t15;
                float bv = b0[n];
#pragma unroll
                for (int r = 0; r < 4; r++) {
                    int m = bm * 128 + wm * 64 + mi * 16 + g * 4 + r;
                    ofp[(size_t)m * DMODEL + n] = acc[mi][ni][r] + bv + resid[(size_t)m * DMODEL + n];
                }
            }
        }
    }
}

// ---------------- Flash attention, causal, exp2-domain, defer-max ----------------
// q (pre-scaled by log2e/8), k bf16 [head][seq][64]; vt bf16 [head][64][seq];
// out bf16 [seq][1024]. r11 structure (KVBLK=128, double buffer, triangle
// pairing, 33 uniform iters). NEW: 1-D grid, h = bid & 15 so bid%8 == h%8 ->
// with round-robin XCD assignment each XCD serves 2 heads; per-XCD working
// set (K,V,Q for 2 heads) = 3MB < 4MB L2 -> kills the 5x L2-thrash refetch.
__global__ __launch_bounds__(256, 2) void attn_kernel(const u16* __restrict__ q,
                                                      const u16* __restrict__ k,
                                                      const u16* __restrict__ vt,
                                                      u16* __restrict__ o) {
    __shared__ alignas(16) u16 Kl[2][128 * 64];   // [kv-row][d]
    __shared__ alignas(16) u16 Vl[2][64 * 128];   // [d][kv-col]
    int bid = blockIdx.x;
    int h = bid & 15;                               // bid%8 == h%8 -> XCD-pinned heads
    int p = bid >> 4;                               // 0..31
    int tid = threadIdx.x, wid = tid >> 6, lane = tid & 63;
    int t15 = lane & 15, g = lane >> 4;
    const u16* Qh  = q  + (size_t)h * SEQLEN * DKDIM;
    const u16* Kh  = k  + (size_t)h * SEQLEN * DKDIM;
    const u16* VtH = vt + (size_t)h * DKDIM * SEQLEN;
    int sslotK = lane & 7;                           // K: 8 slots/row
    int sslotV = lane & 15;                          // V: 16 slots/row

    // stage 128-row K tile + 64x128 V^T tile; 8 loads/wave, linear LDS dest,
    // pre-swizzled global source (slot ^= row&7 on 16B slots)
#define STAGE(b, kt_)                                                                   \
    {                                                                                   \
        int k0s = (kt_) * 128;                                                          \
        _Pragma("unroll")                                                               \
        for (int it = 0; it < 4; it++) {                                                \
            int u    = wid * 4 + it;                 /* 0..15 */                        \
            int krow = u * 8 + (lane >> 3);          /* 0..127 */                       \
            int ksl  = (sslotK ^ (krow & 7)) * 8;                                       \
            ASYNC_COPY16(Kh + (size_t)(k0s + krow) * DKDIM + ksl, &Kl[b][u * 512]);     \
            int vrow = u * 4 + (lane >> 4);          /* 0..63 */                        \
            int vsl  = (sslotV ^ (vrow & 7)) * 8;                                       \
            ASYNC_COPY16(VtH + (size_t)vrow * SEQLEN + k0s + vsl, &Vl[b][u * 512]);     \
        }                                                                               \
    }

    for (int pass = 0; pass < 2; pass++) {
        int qt = pass ? p : (63 - p);                // 64-row q-tile index
        int n = (qt + 2) >> 1;                       // 128-row kv-tiles needed
        int q0 = qt * 64;
        int qrow = q0 + wid * 16 + t15;
        i32x4 qf0, qf1;
        {
            const u16* qp = Qh + (size_t)qrow * DKDIM + g * 8;
            qf0 = *reinterpret_cast<const i32x4*>(qp);
            qf1 = *reinterpret_cast<const i32x4*>(qp + 32);
        }
        f32x4 oacc[4] = {};
        float m_run = -1e30f, l_part = 0.f;

        STAGE(0, 0)
        __syncthreads();
        int buf = 0;
        for (int kt = 0; kt < n; kt++) {
            if (kt + 1 < n) STAGE(buf ^ 1, kt + 1)
            int k0 = kt * 128;
            // ---- S^T = K . Q^T  (exp2 domain via Q prescale), 8 kv-16 blocks ----
            f32x4 sacc[8] = {};
            __builtin_amdgcn_s_setprio(1);
#pragma unroll
            for (int kb = 0; kb < 8; kb++) {
                int j = kb * 16 + t15;
                i32x4 kf0 = *reinterpret_cast<const i32x4*>(&Kl[buf][j * 64 + ((g ^ (j & 7)) * 8)]);
                i32x4 kf1 = *reinterpret_cast<const i32x4*>(&Kl[buf][j * 64 + (((4 + g) ^ (j & 7)) * 8)]);
                mfma_bf16(sacc[kb], kf0, qf0);
                mfma_bf16(sacc[kb], kf1, qf1);
            }
            __builtin_amdgcn_s_setprio(0);
            // ---- causal mask: only the last tile of the pass ----
            if (kt == n - 1) {
#pragma unroll
                for (int kb = 0; kb < 8; kb++)
#pragma unroll
                    for (int r = 0; r < 4; r++) {
                        int kvg = k0 + kb * 16 + g * 4 + r;
                        if (kvg > qrow) sacc[kb][r] = -1e30f;
                    }
            }
            // ---- per-lane tile max (tree) + defer-max ----
            float a0 = fmaxf(fmaxf(sacc[0][0], sacc[0][1]), fmaxf(sacc[0][2], sacc[0][3]));
            float a1 = fmaxf(fmaxf(sacc[1][0], sacc[1][1]), fmaxf(sacc[1][2], sacc[1][3]));
            float a2 = fmaxf(fmaxf(sacc[2][0], sacc[2][1]), fmaxf(sacc[2][2], sacc[2][3]));
            float a3 = fmaxf(fmaxf(sacc[3][0], sacc[3][1]), fmaxf(sacc[3][2], sacc[3][3]));
            float a4 = fmaxf(fmaxf(sacc[4][0], sacc[4][1]), fmaxf(sacc[4][2], sacc[4][3]));
            float a5 = fmaxf(fmaxf(sacc[5][0], sacc[5][1]), fmaxf(sacc[5][2], sacc[5][3]));
            float a6 = fmaxf(fmaxf(sacc[6][0], sacc[6][1]), fmaxf(sacc[6][2], sacc[6][3]));
            float a7 = fmaxf(fmaxf(sacc[7][0], sacc[7][1]), fmaxf(sacc[7][2], sacc[7][3]));
            float mx = fmaxf(fmaxf(fmaxf(a0, a1), fmaxf(a2, a3)),
                             fmaxf(fmaxf(a4, a5), fmaxf(a6, a7)));
            if (!__all(mx <= m_run + 8.0f)) {
                float mrow = fmaxf(mx, __shfl_xor(mx, 16));
                mrow = fmaxf(mrow, __shfl_xor(mrow, 32));
                float mnew = fmaxf(m_run, mrow);
                float fold = exp2a(m_run - mnew);
                m_run = mnew;
                l_part *= fold;
                oacc[0] *= fold; oacc[1] *= fold; oacc[2] *= fold; oacc[3] *= fold;
            }
            // ---- p = exp2(s - m), pack bf16 ----
            float ps = 0.f;
            u32 pw[16];
#pragma unroll
            for (int kb = 0; kb < 8; kb++) {
                float p0 = exp2a(sacc[kb][0] - m_run);
                float p1 = exp2a(sacc[kb][1] - m_run);
                float p2 = exp2a(sacc[kb][2] - m_run);
                float p3 = exp2a(sacc[kb][3] - m_run);
                ps += (p0 + p1) + (p2 + p3);
                pw[kb * 2]     = cvtpk(p0, p1);
                pw[kb * 2 + 1] = cvtpk(p2, p3);
            }
            l_part += ps;
            // ---- O^T += V^T . P^T  (16x16x16, P in B-layout) ----
            __builtin_amdgcn_s_setprio(1);
#pragma unroll
            for (int nb = 0; nb < 4; nb++) {
                int d = nb * 16 + t15;
#pragma unroll
                for (int kb = 0; kb < 8; kb++) {
                    i32x2 vf = *reinterpret_cast<const i32x2*>(
                        &Vl[buf][d * 128 + (((kb * 2 + (g >> 1)) ^ (d & 7)) * 8) + (g & 1) * 4]);
                    i32x2 pf = i32x2{(int)pw[kb * 2], (int)pw[kb * 2 + 1]};
                    mfma16_bf16(oacc[nb], vf, pf);
                }
            }
            __builtin_amdgcn_s_setprio(0);
            __syncthreads();
            buf ^= 1;
        }
        float l = l_part;
        l += __shfl_xor(l, 16);
        l += __shfl_xor(l, 32);
        float inv_l = 1.0f / l;
#pragma unroll
        for (int nb = 0; nb < 4; nb++) {
            ushort4 w4;
            w4.x = f2bf(oacc[nb][0] * inv_l);
            w4.y = f2bf(oacc[nb][1] * inv_l);
            w4.z = f2bf(oacc[nb][2] * inv_l);
            w4.w = f2bf(oacc[nb][3] * inv_l);
            *reinterpret_cast<ushort4*>(&o[(size_t)qrow * DMODEL + h * DKDIM + nb * 16 + g * 4]) = w4;
        }
        __syncthreads();   // protect K/V buffers before next pass's prologue stage
    }
#undef STAGE
}

extern "C" void kernel_launch(void* const* d_in, const int* in_sizes, int n_in,
                              void* d_out, int out_size, void* d_ws, size_t ws_size,
                              hipStream_t stream) {
    const float* h     = (const float*)d_in[0];
    const float* gamma = (const float*)d_in[1];
    const float* beta  = (const float*)d_in[2];
    const float* Wq    = (const float*)d_in[3];
    const float* bq    = (const float*)d_in[4];
    const float* Wk    = (const float*)d_in[5];
    const float* bk    = (const float*)d_in[6];
    const float* Wv    = (const float*)d_in[7];
    const float* bv    = (const float*)d_in[8];
    const float* Wo    = (const float*)d_in[9];
    const float* bo    = (const float*)d_in[10];
    float* out = (float*)d_out;

    char* ws = (char*)d_ws;
    u16* hn     = (u16*)(ws);                        // 8 MiB; reused as attn output
    u16* wqkvT  = (u16*)(ws + (8ull  << 20));        // 6 MiB [3072][1024]
    u16* woT    = (u16*)(ws + (14ull << 20));        // 2 MiB
    u16* qb     = (u16*)(ws + (16ull << 20));        // [16][4096][64]
    u16* kbuf   = (u16*)(ws + (24ull << 20));        // [16][4096][64]
    u16* vtb    = (u16*)(ws + (32ull << 20));        // [16][64][4096]
    float* cosT = (float*)(ws + (40ull << 20));
    float* sinT = (float*)(ws + (40ull << 20) + (512ull << 10));
    u16* attn = hn;

    ln_kernel<<<SEQLEN, 256, 0, stream>>>(h, gamma, beta, hn);
    wconv_kernel<<<dim3(32, 32, 4), 256, 0, stream>>>(Wq, Wk, Wv, Wo, wqkvT, woT);
    rope_table_kernel<<<(SEQLEN * 32) / 256, 256, 0, stream>>>(cosT, sinT);
    gemm_kernel<0><<<dim3(32, 24), 256, 0, stream>>>(hn, wqkvT, bq, bk, bv, nullptr,
                                                     cosT, sinT, qb, kbuf, vtb, nullptr);
    attn_kernel<<<512, 256, 0, stream>>>(qb, kbuf, vtb, attn);
    gemm_kernel<1><<<dim3(32, 8), 256, 0, stream>>>(attn, woT, bo, nullptr, nullptr, h,
                                                    nullptr, nullptr, nullptr, nullptr, nullptr, out);
}

// Round 13
// 136.476 us; speedup vs baseline: 1.8727x; 1.0534x over previous
//
#include <hip/hip_runtime.h>
#include <stdint.h>

#define SEQLEN 4096
#define DMODEL 1024
#define NHEADS 16
#define DKDIM  64

typedef unsigned short u16;
typedef unsigned int   u32;
using f32x4 = __attribute__((ext_vector_type(4))) float;
using i32x4 = __attribute__((ext_vector_type(4))) int;
using i32x2 = __attribute__((ext_vector_type(2))) int;
using u16x8 = __attribute__((ext_vector_type(8))) unsigned short;

__device__ __forceinline__ u16 f2bf(float f) {
    u32 x = __builtin_bit_cast(u32, f);
    u32 r = x + 0x7fffu + ((x >> 16) & 1u);   // RNE
    return (u16)(r >> 16);
}
__device__ __forceinline__ float exp2a(float x) {
    float r; asm("v_exp_f32 %0, %1" : "=v"(r) : "v"(x)); return r;
}
__device__ __forceinline__ u32 cvtpk(float lo, float hi) {
    u32 r; asm("v_cvt_pk_bf16_f32 %0, %1, %2" : "=v"(r) : "v"(lo), "v"(hi)); return r;
}

// 16x16x32: A lane holds A[lane&15][(lane>>4)*8+j]; B: B[(lane>>4)*8+j][lane&15];
// C/D: D[(lane>>4)*4+r][lane&15]
__device__ __forceinline__ void mfma_bf16(f32x4& d, i32x4 a, i32x4 b) {
    asm("v_mfma_f32_16x16x32_bf16 %0, %1, %2, %0" : "+v"(d) : "v"(a), "v"(b));
}
// 16x16x16: A lane holds A[lane&15][(lane>>4)*4+j]; B: B[(lane>>4)*4+j][lane&15]
__device__ __forceinline__ void mfma16_bf16(f32x4& d, i32x2 a, i32x2 b) {
    asm("v_mfma_f32_16x16x16_bf16 %0, %1, %2, %0" : "+v"(d) : "v"(a), "v"(b));
}

// async global->LDS, 16B per lane; LDS dest = wave-uniform base + lane*16
#define ASYNC_COPY16(gsrc, ldst) \
    __builtin_amdgcn_global_load_lds((const __attribute__((address_space(1))) void*)(gsrc), \
                                     (__attribute__((address_space(3))) void*)(ldst), 16, 0, 0)

// ---------------- LayerNorm: h fp32 [4096][1024] -> hn bf16 ----------------
__global__ __launch_bounds__(256) void ln_kernel(const float* __restrict__ h,
                                                 const float* __restrict__ gamma,
                                                 const float* __restrict__ beta,
                                                 u16* __restrict__ hn) {
    int row = blockIdx.x;
    int t = threadIdx.x;
    float4 v = reinterpret_cast<const float4*>(h + (size_t)row * DMODEL)[t];
    float s  = v.x + v.y + v.z + v.w;
    float s2 = v.x*v.x + v.y*v.y + v.z*v.z + v.w*v.w;
#pragma unroll
    for (int off = 1; off < 64; off <<= 1) {
        s  += __shfl_xor(s, off);
        s2 += __shfl_xor(s2, off);
    }
    __shared__ float red[8];
    int wid = t >> 6, lane = t & 63;
    if (lane == 0) { red[wid] = s; red[4 + wid] = s2; }
    __syncthreads();
    s  = red[0] + red[1] + red[2] + red[3];
    s2 = red[4] + red[5] + red[6] + red[7];
    float mu   = s * (1.0f / DMODEL);
    float rstd = rsqrtf(s2 * (1.0f / DMODEL) - mu * mu + 1e-5f);
    float4 g = reinterpret_cast<const float4*>(gamma)[t];
    float4 b = reinterpret_cast<const float4*>(beta)[t];
    ushort4 o;
    o.x = f2bf((v.x - mu) * rstd * g.x + b.x);
    o.y = f2bf((v.y - mu) * rstd * g.y + b.y);
    o.z = f2bf((v.z - mu) * rstd * g.z + b.z);
    o.w = f2bf((v.w - mu) * rstd * g.w + b.w);
    reinterpret_cast<ushort4*>(hn + (size_t)row * DMODEL)[t] = o;
}

// ---- Weight transpose+convert (all 4 weights): W fp32 [K][N] -> Wt bf16 [N][K] ----
__global__ __launch_bounds__(256) void wconv_kernel(const float* __restrict__ Wq,
                                                    const float* __restrict__ Wk,
                                                    const float* __restrict__ Wv,
                                                    const float* __restrict__ Wo,
                                                    u16* __restrict__ wqkvT,
                                                    u16* __restrict__ woT) {
    int z = blockIdx.z;
    const float* W = (z == 0) ? Wq : (z == 1) ? Wk : (z == 2) ? Wv : Wo;
    u16* Wt = (z < 3) ? wqkvT + (size_t)z * DMODEL * DMODEL : woT;
    __shared__ float tile[32][33];
    int bx = blockIdx.x * 32;   // n
    int by = blockIdx.y * 32;   // k
    int tx = threadIdx.x & 31, ty = threadIdx.x >> 5;
#pragma unroll
    for (int i = 0; i < 32; i += 8)
        tile[ty + i][tx] = W[(size_t)(by + ty + i) * DMODEL + bx + tx];
    __syncthreads();
#pragma unroll
    for (int i = 0; i < 32; i += 8)
        Wt[(size_t)(bx + ty + i) * DMODEL + by + tx] = f2bf(tile[tx][ty + i]);
}

// ---------------- RoPE cos/sin tables: [4096][32] fp32 each ----------------
__global__ void rope_table_kernel(float* __restrict__ cosT, float* __restrict__ sinT) {
    int idx = blockIdx.x * 256 + threadIdx.x;
    int s = idx >> 5, i = idx & 31;
    float theta = powf(10000.0f, -2.0f * (float)i / 64.0f);
    float ang = (float)s * theta;
    cosT[idx] = cosf(ang);
    sinT[idx] = sinf(ang);
}

// ---------------- GEMM: 128x128 tile, BK=64, global_load_lds double-buffer ----------------
// EPI=0: merged QKV (Bt rows 0..3071). seg=bn>>3: 0=Q (RoPE, *log2e/8 -> o0),
//        1=K (RoPE -> o1), 2=V (write V^T [head][64][seq] -> o2).
// EPI=1: +bias +residual, fp32 [seq][1024] -> ofp.
template <int EPI>
__global__ __launch_bounds__(256) void gemm_kernel(const u16* __restrict__ A,
                                                   const u16* __restrict__ Bt,
                                                   const float* __restrict__ b0,
                                                   const float* __restrict__ b1,
                                                   const float* __restrict__ b2,
                                                   const float* __restrict__ resid,
                                                   const float* __restrict__ cosT,
                                                   const float* __restrict__ sinT,
                                                   u16* __restrict__ o0,
                                                   u16* __restrict__ o1,
                                                   u16* __restrict__ o2,
                                                   float* __restrict__ ofp) {
    __shared__ alignas(16) u16 As[2][128 * 64];
    __shared__ alignas(16) u16 Bs[2][128 * 64];
    int bm = blockIdx.x, bn = blockIdx.y;
    int tid = threadIdx.x;
    int wid = tid >> 6, lane = tid & 63;
    int wm = wid >> 1, wn = wid & 1;
    int t15 = lane & 15, g = lane >> 4;
    const u16* Abase = A  + (size_t)bm * 128 * DMODEL;
    const u16* Bbase = Bt + (size_t)bn * 128 * DMODEL;
    int srow = tid >> 3;          // 0..31 within each 32-row issue chunk
    int sslot = tid & 7;
    f32x4 acc[4][4] = {};

    // LDS[row][slot] = global[row][slot ^ (row&7)]  (slots of 8 elems = 16B)
#define GSTAGE(b, ks)                                                                    \
    {                                                                                    \
        _Pragma("unroll")                                                                \
        for (int i = 0; i < 4; i++) {                                                    \
            int row = i * 32 + srow;                                                     \
            int col = ((sslot ^ (row & 7)) * 8) + (ks);                                  \
            ASYNC_COPY16(Abase + (size_t)row * DMODEL + col, &As[b][i * 2048 + wid * 512]); \
            ASYNC_COPY16(Bbase + (size_t)row * DMODEL + col, &Bs[b][i * 2048 + wid * 512]); \
        }                                                                                \
    }

    GSTAGE(0, 0)
    __syncthreads();
    int buf = 0;
    for (int ks = 0; ks < DMODEL; ks += 64) {
        if (ks < DMODEL - 64) GSTAGE(buf ^ 1, ks + 64)
#pragma unroll
        for (int kk = 0; kk < 2; kk++) {
            i32x4 af[4], bfr[4];
#pragma unroll
            for (int mi = 0; mi < 4; mi++) {
                int row = wm * 64 + mi * 16 + t15;
                int sl = (kk * 4 + g) ^ (row & 7);
                af[mi] = *reinterpret_cast<const i32x4*>(&As[buf][row * 64 + sl * 8]);
            }
#pragma unroll
            for (int ni = 0; ni < 4; ni++) {
                int row = wn * 64 + ni * 16 + t15;
                int sl = (kk * 4 + g) ^ (row & 7);
                bfr[ni] = *reinterpret_cast<const i32x4*>(&Bs[buf][row * 64 + sl * 8]);
            }
            __builtin_amdgcn_s_setprio(1);
#pragma unroll
            for (int mi = 0; mi < 4; mi++)
#pragma unroll
                for (int ni = 0; ni < 4; ni++)
                    mfma_bf16(acc[mi][ni], af[mi], bfr[ni]);
            __builtin_amdgcn_s_setprio(0);
        }
        __syncthreads();
        buf ^= 1;
    }
#undef GSTAGE

    if (EPI == 0) {
        int seg = bn >> 3;                 // 0=Q 1=K 2=V
        int bnl = bn & 7;
        const float* bias = (seg == 0) ? b0 : (seg == 1) ? b1 : b2;
        if (seg < 2) {
            u16* o = (seg == 0) ? o0 : o1;
            float qs = (seg == 0) ? 0.18033688f : 1.0f;   // log2(e)/8 for Q
#pragma unroll
            for (int mi = 0; mi < 4; mi++) {
#pragma unroll
                for (int nl = 0; nl < 2; nl++) {
                    int n10 = bnl * 128 + wn * 64 + nl * 16 + t15;  // d&63 in 0..31
                    int head = n10 >> 6;
                    int dA = n10 & 63, dB = dA + 32;
                    float bvA = bias[n10], bvB = bias[n10 + 32];
#pragma unroll
                    for (int r = 0; r < 4; r++) {
                        int m = bm * 128 + wm * 64 + mi * 16 + g * 4 + r;
                        float c  = cosT[m * 32 + dA];
                        float sn = sinT[m * 32 + dA];
                        float xA = acc[mi][nl][r] + bvA;
                        float xB = acc[mi][nl + 2][r] + bvB;
                        o[(size_t)(head * SEQLEN + m) * DKDIM + dA] = f2bf((xA * c - xB * sn) * qs);
                        o[(size_t)(head * SEQLEN + m) * DKDIM + dB] = f2bf((xB * c + xA * sn) * qs);
                    }
                }
            }
        } else {
#pragma unroll
            for (int mi = 0; mi < 4; mi++) {
#pragma unroll
                for (int ni = 0; ni < 4; ni++) {
                    int n10 = bnl * 128 + wn * 64 + ni * 16 + t15;
                    int head = n10 >> 6, dv = n10 & 63;
                    float bv = bias[n10];
                    int m = bm * 128 + wm * 64 + mi * 16 + g * 4;
                    ushort4 w4;
                    w4.x = f2bf(acc[mi][ni][0] + bv);
                    w4.y = f2bf(acc[mi][ni][1] + bv);
                    w4.z = f2bf(acc[mi][ni][2] + bv);
                    w4.w = f2bf(acc[mi][ni][3] + bv);
                    *reinterpret_cast<ushort4*>(&o2[(size_t)(head * DKDIM + dv) * SEQLEN + m]) = w4;
                }
            }
        }
    } else {
#pragma unroll
        for (int mi = 0; mi < 4; mi++) {
#pragma unroll
            for (int ni = 0; ni < 4; ni++) {
                int n = bn * 128 + wn * 64 + ni * 16 + t15;
                float bv = b0[n];
#pragma unroll
                for (int r = 0; r < 4; r++) {
                    int m = bm * 128 + wm * 64 + mi * 16 + g * 4 + r;
                    ofp[(size_t)m * DMODEL + n] = acc[mi][ni][r] + bv + resid[(size_t)m * DMODEL + n];
                }
            }
        }
    }
}

// ---------------- Flash attention, causal, exp2-domain, defer-max ----------------
// q (pre-scaled by log2e/8), k bf16 [head][seq][64]; vt bf16 [head][64][seq];
// out bf16 [seq][1024].
// 512-thread block = 2 groups x 4 waves. Each wave: 32 q-rows (two 16-row
// B-frags) -> group covers a 128-row Q tile. Groups split kv-tiles even/odd
// (block-local split-K); 2-way LDS merge at pass end (aliased onto dead K/V
// buffers). Triangle pairing {31-p, p} -> 17 uniform barrier intervals per
// group per pass-pair; 256 blocks (1/CU, 8 waves = 2/SIMD). h = bid&15 keeps
// XCD head pinning (r12 win: FETCH 134->12 MB).
__global__ __launch_bounds__(512, 2) void attn_kernel(const u16* __restrict__ q,
                                                      const u16* __restrict__ k,
                                                      const u16* __restrict__ vt,
                                                      u16* __restrict__ o) {
    __shared__ alignas(16) u16 SMEM[65536];   // 128 KB: K 4x16KB | V 4x16KB; merge aliases
    int bid = blockIdx.x;
    int h = bid & 15;                          // XCD-pinned heads
    int p = bid >> 4;                          // 0..15
    int tid = threadIdx.x;
    int grp = tid >> 8;                        // 0/1: kv-chunk group
    int wid = (tid >> 6) & 3;                  // wave within group
    int lane = tid & 63;
    int t15 = lane & 15, g = lane >> 4;
    const u16* Qh  = q  + (size_t)h * SEQLEN * DKDIM;
    const u16* Kh  = k  + (size_t)h * SEQLEN * DKDIM;
    const u16* VtH = vt + (size_t)h * DKDIM * SEQLEN;
    int sslotK = lane & 7;
    int sslotV = lane & 15;
    float* Os  = (float*)SMEM;                              // [2][128][68] fp32 (alias)
    float2* Ml = (float2*)((char*)SMEM + 69632);            // [2][128]

    // stage 128-row K tile + 64x128 V^T tile for THIS group; linear LDS dest,
    // pre-swizzled global source (16B slot ^= row&7)
#define STAGE(bb, t_)                                                                   \
    {                                                                                   \
        int k0s = (t_) * 128;                                                           \
        u16* Kb = SMEM + (size_t)(grp * 2 + (bb)) * 8192;                               \
        u16* Vb = SMEM + 32768 + (size_t)(grp * 2 + (bb)) * 8192;                       \
        _Pragma("unroll")                                                               \
        for (int it = 0; it < 4; it++) {                                                \
            int u    = wid * 4 + it;                                                    \
            int krow = u * 8 + (lane >> 3);                                             \
            int ksl  = (sslotK ^ (krow & 7)) * 8;                                       \
            ASYNC_COPY16(Kh + (size_t)(k0s + krow) * DKDIM + ksl, Kb + u * 512);        \
            int vrow = u * 4 + (lane >> 4);                                             \
            int vsl  = (sslotV ^ (vrow & 7)) * 8;                                       \
            ASYNC_COPY16(VtH + (size_t)vrow * SEQLEN + k0s + vsl, Vb + u * 512);        \
        }                                                                               \
    }

    for (int pass = 0; pass < 2; pass++) {
        int Q = pass ? p : (31 - p);             // 128-row q-tile index
        int n = Q + 1;                           // 128-row kv-tiles
        int iters = (n + 1) >> 1;                // identical for both groups
        int q0 = Q * 128;
        int qrowA = q0 + wid * 32 + t15;
        int qrowB = qrowA + 16;
        i32x4 qfA0, qfA1, qfB0, qfB1;
        {
            const u16* qp = Qh + (size_t)qrowA * DKDIM + g * 8;
            qfA0 = *reinterpret_cast<const i32x4*>(qp);
            qfA1 = *reinterpret_cast<const i32x4*>(qp + 32);
            const u16* qp2 = qp + 16 * DKDIM;
            qfB0 = *reinterpret_cast<const i32x4*>(qp2);
            qfB1 = *reinterpret_cast<const i32x4*>(qp2 + 32);
        }
        f32x4 oA[4] = {}, oB[4] = {};
        float mA = -1e30f, mB = -1e30f, lA = 0.f, lB = 0.f;

        if (grp < n) STAGE(0, grp)
        __syncthreads();
        for (int i = 0; i < iters; i++) {
            int t = grp + 2 * i;
            bool active = t < n;
            int buf = i & 1;
            if (t + 2 < n) STAGE(buf ^ 1, t + 2)
            if (active) {
                const u16* Kb = SMEM + (size_t)(grp * 2 + buf) * 8192;
                const u16* Vb = SMEM + 32768 + (size_t)(grp * 2 + buf) * 8192;
                int k0 = t * 128;
                // ---- S^T = K . Q^T for both frags (K-frags read once) ----
                f32x4 sA[8] = {}, sB[8] = {};
                __builtin_amdgcn_s_setprio(1);
#pragma unroll
                for (int kb = 0; kb < 8; kb++) {
                    int j = kb * 16 + t15;
                    i32x4 kf0 = *reinterpret_cast<const i32x4*>(&Kb[j * 64 + ((g ^ (j & 7)) * 8)]);
                    i32x4 kf1 = *reinterpret_cast<const i32x4*>(&Kb[j * 64 + (((4 + g) ^ (j & 7)) * 8)]);
                    mfma_bf16(sA[kb], kf0, qfA0);
                    mfma_bf16(sA[kb], kf1, qfA1);
                    mfma_bf16(sB[kb], kf0, qfB0);
                    mfma_bf16(sB[kb], kf1, qfB1);
                }
                __builtin_amdgcn_s_setprio(0);
                // ---- causal mask: only the diagonal tile (t == Q) ----
                if (t == n - 1) {
#pragma unroll
                    for (int kb = 0; kb < 8; kb++)
#pragma unroll
                        for (int r = 0; r < 4; r++) {
                            int kvg = k0 + kb * 16 + g * 4 + r;
                            if (kvg > qrowA) sA[kb][r] = -1e30f;
                            if (kvg > qrowB) sB[kb][r] = -1e30f;
                        }
                }
                // ---- per-lane tile max (tree) + defer-max (combined) ----
                float amx[8], bmx[8];
#pragma unroll
                for (int kb = 0; kb < 8; kb++) {
                    amx[kb] = fmaxf(fmaxf(sA[kb][0], sA[kb][1]), fmaxf(sA[kb][2], sA[kb][3]));
                    bmx[kb] = fmaxf(fmaxf(sB[kb][0], sB[kb][1]), fmaxf(sB[kb][2], sB[kb][3]));
                }
                float mxA = fmaxf(fmaxf(fmaxf(amx[0], amx[1]), fmaxf(amx[2], amx[3])),
                                  fmaxf(fmaxf(amx[4], amx[5]), fmaxf(amx[6], amx[7])));
                float mxB = fmaxf(fmaxf(fmaxf(bmx[0], bmx[1]), fmaxf(bmx[2], bmx[3])),
                                  fmaxf(fmaxf(bmx[4], bmx[5]), fmaxf(bmx[6], bmx[7])));
                if (!__all((mxA <= mA + 8.0f) && (mxB <= mB + 8.0f))) {
                    float mrA = fmaxf(mxA, __shfl_xor(mxA, 16));
                    mrA = fmaxf(mrA, __shfl_xor(mrA, 32));
                    float mnA = fmaxf(mA, mrA);
                    float fdA = exp2a(mA - mnA);
                    mA = mnA; lA *= fdA;
                    oA[0] *= fdA; oA[1] *= fdA; oA[2] *= fdA; oA[3] *= fdA;
                    float mrB = fmaxf(mxB, __shfl_xor(mxB, 16));
                    mrB = fmaxf(mrB, __shfl_xor(mrB, 32));
                    float mnB = fmaxf(mB, mrB);
                    float fdB = exp2a(mB - mnB);
                    mB = mnB; lB *= fdB;
                    oB[0] *= fdB; oB[1] *= fdB; oB[2] *= fdB; oB[3] *= fdB;
                }
                // ---- p = exp2(s - m), pack bf16 ----
                float psA = 0.f, psB = 0.f;
                u32 pwA[16], pwB[16];
#pragma unroll
                for (int kb = 0; kb < 8; kb++) {
                    float pa0 = exp2a(sA[kb][0] - mA);
                    float pa1 = exp2a(sA[kb][1] - mA);
                    float pa2 = exp2a(sA[kb][2] - mA);
                    float pa3 = exp2a(sA[kb][3] - mA);
                    psA += (pa0 + pa1) + (pa2 + pa3);
                    pwA[kb * 2]     = cvtpk(pa0, pa1);
                    pwA[kb * 2 + 1] = cvtpk(pa2, pa3);
                    float pb0 = exp2a(sB[kb][0] - mB);
                    float pb1 = exp2a(sB[kb][1] - mB);
                    float pb2 = exp2a(sB[kb][2] - mB);
                    float pb3 = exp2a(sB[kb][3] - mB);
                    psB += (pb0 + pb1) + (pb2 + pb3);
                    pwB[kb * 2]     = cvtpk(pb0, pb1);
                    pwB[kb * 2 + 1] = cvtpk(pb2, pb3);
                }
                lA += psA;
                lB += psB;
                // ---- O^T += V^T . P^T  (V-frags read once, feed both frags) ----
                __builtin_amdgcn_s_setprio(1);
#pragma unroll
                for (int nb = 0; nb < 4; nb++) {
                    int d = nb * 16 + t15;
#pragma unroll
                    for (int kb = 0; kb < 8; kb++) {
                        i32x2 vf = *reinterpret_cast<const i32x2*>(
                            &Vb[d * 128 + (((kb * 2 + (g >> 1)) ^ (d & 7)) * 8) + (g & 1) * 4]);
                        mfma16_bf16(oA[nb], vf, i32x2{(int)pwA[kb * 2], (int)pwA[kb * 2 + 1]});
                        mfma16_bf16(oB[nb], vf, i32x2{(int)pwB[kb * 2], (int)pwB[kb * 2 + 1]});
                    }
                }
                __builtin_amdgcn_s_setprio(0);
            }
            __syncthreads();
        }
        // ---- reduce l across the 4 k-slot lanes of each q-row ----
        lA += __shfl_xor(lA, 16); lA += __shfl_xor(lA, 32);
        lB += __shfl_xor(lB, 16); lB += __shfl_xor(lB, 32);
        // ---- write partials to LDS (aliases dead K/V buffers) ----
        int rowA = wid * 32 + t15, rowB = rowA + 16;
#pragma unroll
        for (int nb = 0; nb < 4; nb++) {
            *reinterpret_cast<f32x4*>(&Os[(size_t)(grp * 128 + rowA) * 68 + nb * 16 + g * 4]) = oA[nb];
            *reinterpret_cast<f32x4*>(&Os[(size_t)(grp * 128 + rowB) * 68 + nb * 16 + g * 4]) = oB[nb];
        }
        if (g == 0) {
            Ml[grp * 128 + rowA] = make_float2(mA, lA);
            Ml[grp * 128 + rowB] = make_float2(mB, lB);
        }
        __syncthreads();
        // ---- 2-way merge + normalize + store ----
        {
            int r = tid >> 2, c4 = tid & 3;
            int d0 = c4 * 16;
            float2 c0 = Ml[r], c1 = Ml[128 + r];
            float M = fmaxf(c0.x, c1.x);
            float w0 = exp2a(c0.x - M), w1 = exp2a(c1.x - M);
            float invL = 1.0f / (w0 * c0.y + w1 * c1.y);
            u16* op = o + (size_t)(q0 + r) * DMODEL + h * DKDIM + d0;
#pragma unroll
            for (int j = 0; j < 2; j++) {
                f32x4 a0 = *reinterpret_cast<const f32x4*>(&Os[(size_t)r * 68 + d0 + j * 8]);
                f32x4 a1 = *reinterpret_cast<const f32x4*>(&Os[(size_t)r * 68 + d0 + j * 8 + 4]);
                f32x4 b0 = *reinterpret_cast<const f32x4*>(&Os[(size_t)(128 + r) * 68 + d0 + j * 8]);
                f32x4 b1 = *reinterpret_cast<const f32x4*>(&Os[(size_t)(128 + r) * 68 + d0 + j * 8 + 4]);
                u16x8 w8;
#pragma unroll
                for (int ii = 0; ii < 4; ii++) {
                    w8[ii]     = f2bf((w0 * a0[ii] + w1 * b0[ii]) * invL);
                    w8[4 + ii] = f2bf((w0 * a1[ii] + w1 * b1[ii]) * invL);
                }
                *reinterpret_cast<u16x8*>(op + j * 8) = w8;
            }
        }
        __syncthreads();   // merge reads done before next pass stages over Os
    }
#undef STAGE
}

extern "C" void kernel_launch(void* const* d_in, const int* in_sizes, int n_in,
                              void* d_out, int out_size, void* d_ws, size_t ws_size,
                              hipStream_t stream) {
    const float* h     = (const float*)d_in[0];
    const float* gamma = (const float*)d_in[1];
    const float* beta  = (const float*)d_in[2];
    const float* Wq    = (const float*)d_in[3];
    const float* bq    = (const float*)d_in[4];
    const float* Wk    = (const float*)d_in[5];
    const float* bk    = (const float*)d_in[6];
    const float* Wv    = (const float*)d_in[7];
    const float* bv    = (const float*)d_in[8];
    const float* Wo    = (const float*)d_in[9];
    const float* bo    = (const float*)d_in[10];
    float* out = (float*)d_out;

    char* ws = (char*)d_ws;
    u16* hn     = (u16*)(ws);                        // 8 MiB; reused as attn output
    u16* wqkvT  = (u16*)(ws + (8ull  << 20));        // 6 MiB [3072][1024]
    u16* woT    = (u16*)(ws + (14ull << 20));        // 2 MiB
    u16* qb     = (u16*)(ws + (16ull << 20));        // [16][4096][64]
    u16* kbuf   = (u16*)(ws + (24ull << 20));        // [16][4096][64]
    u16* vtb    = (u16*)(ws + (32ull << 20));        // [16][64][4096]
    float* cosT = (float*)(ws + (40ull << 20));
    float* sinT = (float*)(ws + (40ull << 20) + (512ull << 10));
    u16* attn = hn;

    ln_kernel<<<SEQLEN, 256, 0, stream>>>(h, gamma, beta, hn);
    wconv_kernel<<<dim3(32, 32, 4), 256, 0, stream>>>(Wq, Wk, Wv, Wo, wqkvT, woT);
    rope_table_kernel<<<(SEQLEN * 32) / 256, 256, 0, stream>>>(cosT, sinT);
    gemm_kernel<0><<<dim3(32, 24), 256, 0, stream>>>(hn, wqkvT, bq, bk, bv, nullptr,
                                                     cosT, sinT, qb, kbuf, vtb, nullptr);
    attn_kernel<<<256, 512, 0, stream>>>(qb, kbuf, vtb, attn);
    gemm_kernel<1><<<dim3(32, 8), 256, 0, stream>>>(attn, woT, bo, nullptr, nullptr, h,
                                                    nullptr, nullptr, nullptr, nullptr, nullptr, out);
}